// Round 1
// baseline (7266.309 us; speedup 1.0000x reference)
//
#include <hip/hip_runtime.h>
#include <math.h>

// PredictorNoEgo: B=8192 T=8 E=256 M=20 FS=12
// Key algebraic facts used:
//  - softmax over size-1 axis == 1  =>  ctx == v  (q,k dead)
//  - attn_out = emb @ (out_w[m] @ Wv[m])^T + (out_w[m]@bv[m] + out_b[m])
#define LDP 260   // padded stride for 64x256 activation tiles in LDS
#define BST 312   // swizzled B-tile stride

typedef float4 f4;

__device__ __forceinline__ float sigm(float x){ return 1.0f/(1.0f + __expf(-x)); }
__device__ __forceinline__ float eluf(float x){ return x > 0.f ? x : expm1f(x); }

// ---------------------------------------------------------------------------
// W2c[m] = out_w[m] (256x256) @ in_proj_w[m,512:768,:] (256x256)
__global__ __launch_bounds__(256, 4)
void w2c_kernel(const float* __restrict__ out_w, const float* __restrict__ ipw,
                float* __restrict__ W2c)
{
  __shared__ float As[16][68];
  __shared__ float Bs[16][68];
  const int tid = threadIdx.x;
  const int m = blockIdx.y;
  const int o0 = (blockIdx.x >> 2) * 64, e0 = (blockIdx.x & 3) * 64;
  const int trow = tid >> 4, tcol = tid & 15;
  const float* Ap = out_w + (size_t)m * 65536;
  const float* Bp = ipw + ((size_t)m * 768 + 512) * 256;
  float acc[16];
#pragma unroll
  for (int z = 0; z < 16; ++z) acc[z] = 0.f;
  for (int kb = 0; kb < 256; kb += 16) {
    { int row = tid >> 2, ko = (tid & 3) * 4;
      f4 v = *(const f4*)(Ap + (size_t)(o0+row)*256 + kb + ko);
      As[ko+0][row]=v.x; As[ko+1][row]=v.y; As[ko+2][row]=v.z; As[ko+3][row]=v.w; }
    { int k = tid >> 4, eo = (tid & 15) * 4;
      *(f4*)&Bs[k][eo] = *(const f4*)(Bp + (size_t)(kb+k)*256 + e0 + eo); }
    __syncthreads();
#pragma unroll
    for (int k = 0; k < 16; ++k) {
      f4 a4 = *(const f4*)&As[k][trow*4];
      f4 b4 = *(const f4*)&Bs[k][tcol*4];
      acc[0]+=a4.x*b4.x; acc[1]+=a4.x*b4.y; acc[2]+=a4.x*b4.z; acc[3]+=a4.x*b4.w;
      acc[4]+=a4.y*b4.x; acc[5]+=a4.y*b4.y; acc[6]+=a4.y*b4.z; acc[7]+=a4.y*b4.w;
      acc[8]+=a4.z*b4.x; acc[9]+=a4.z*b4.y; acc[10]+=a4.z*b4.z; acc[11]+=a4.z*b4.w;
      acc[12]+=a4.w*b4.x; acc[13]+=a4.w*b4.y; acc[14]+=a4.w*b4.z; acc[15]+=a4.w*b4.w;
    }
    __syncthreads();
  }
#pragma unroll
  for (int i = 0; i < 4; ++i)
    *(f4*)&W2c[((size_t)m*256 + o0 + trow*4 + i)*256 + e0 + tcol*4] =
        make_float4(acc[i*4+0], acc[i*4+1], acc[i*4+2], acc[i*4+3]);
}

// b2c[m,o] = out_b[m,o] + sum_f out_w[m,o,f]*in_proj_b[m,512+f]
__global__ void b2c_kernel(const float* __restrict__ out_w, const float* __restrict__ out_b,
                           const float* __restrict__ ipb, float* __restrict__ b2c)
{
  __shared__ float pb[256];
  const int m = blockIdx.x, o = threadIdx.x;
  pb[o] = ipb[(size_t)m*768 + 512 + o];
  __syncthreads();
  const float* wr = out_w + ((size_t)m*256 + o)*256;
  float acc = out_b[(size_t)m*256 + o];
  for (int f = 0; f < 256; f += 4) {
    f4 w = *(const f4*)&wr[f];
    acc += w.x*pb[f] + w.y*pb[f+1] + w.z*pb[f+2] + w.w*pb[f+3];
  }
  b2c[(size_t)m*256 + o] = acc;
}

// ---------------------------------------------------------------------------
// One LSTM time-step. Block: 64 batch rows x (4 gates x 32 e-cols).
// IH: full-K GEMM with a_ih (layer1 x-term); HH: GEMM with previous h.
// L0: rank-2 x-term (input dim 2) added in epilogue. !HH => t==0 (c=0).
template<bool IH, bool HH, bool L0>
__global__ __launch_bounds__(512, 4)
void lstm_step(const float* __restrict__ a_ih, const float* __restrict__ a_hh,
               const float* __restrict__ w_ih, const float* __restrict__ w_hh,
               const float* __restrict__ b_ih, const float* __restrict__ b_hh,
               const float* __restrict__ obs, int t,
               float* __restrict__ h, float* __restrict__ c)
{
  __shared__ float As[16][68];
  __shared__ float Bs[16][132];
  __shared__ float Gs[64][132];
  const int tid = threadIdx.x;
  const int r0 = blockIdx.x * 64, e0 = blockIdx.y * 32;
  const int trow = tid >> 5, tcol = tid & 31;
  float acc[16];
#pragma unroll
  for (int z = 0; z < 16; ++z) acc[z] = 0.f;

  auto gphase = [&](const float* __restrict__ Ag, const float* __restrict__ Wg) {
    for (int kb = 0; kb < 256; kb += 16) {
      if (tid < 256) {
        int row = tid >> 2, ko = (tid & 3) * 4;
        f4 v = *(const f4*)(Ag + (size_t)(r0 + row) * 256 + kb + ko);
        As[ko+0][row]=v.x; As[ko+1][row]=v.y; As[ko+2][row]=v.z; As[ko+3][row]=v.w;
      }
      {
        int cc = tid >> 2, ko = (tid & 3) * 4;
        int jr = ((cc >> 5) << 8) + e0 + (cc & 31);  // gate*256 + e
        f4 v = *(const f4*)(Wg + (size_t)jr * 256 + kb + ko);
        Bs[ko+0][cc]=v.x; Bs[ko+1][cc]=v.y; Bs[ko+2][cc]=v.z; Bs[ko+3][cc]=v.w;
      }
      __syncthreads();
#pragma unroll
      for (int k = 0; k < 16; ++k) {
        f4 a4 = *(const f4*)&As[k][trow*4];
        f4 b4 = *(const f4*)&Bs[k][tcol*4];
        acc[0]+=a4.x*b4.x; acc[1]+=a4.x*b4.y; acc[2]+=a4.x*b4.z; acc[3]+=a4.x*b4.w;
        acc[4]+=a4.y*b4.x; acc[5]+=a4.y*b4.y; acc[6]+=a4.y*b4.z; acc[7]+=a4.y*b4.w;
        acc[8]+=a4.z*b4.x; acc[9]+=a4.z*b4.y; acc[10]+=a4.z*b4.z; acc[11]+=a4.z*b4.w;
        acc[12]+=a4.w*b4.x; acc[13]+=a4.w*b4.y; acc[14]+=a4.w*b4.z; acc[15]+=a4.w*b4.w;
      }
      __syncthreads();
    }
  };
  if (IH) gphase(a_ih, w_ih);
  if (HH) gphase(a_hh, w_hh);

#pragma unroll
  for (int i = 0; i < 4; ++i)
    *(f4*)&Gs[trow*4+i][tcol*4] = make_float4(acc[i*4+0], acc[i*4+1], acc[i*4+2], acc[i*4+3]);
  __syncthreads();

#pragma unroll
  for (int it = 0; it < 4; ++it) {
    int idx = tid + 512*it;
    int row = idx >> 5, e = idx & 31;
    int bg = r0 + row, eg = e0 + e;
    float gi = Gs[row][e], gf = Gs[row][32+e], gg = Gs[row][64+e], go = Gs[row][96+e];
    gi += b_ih[eg]     + b_hh[eg];
    gf += b_ih[256+eg] + b_hh[256+eg];
    gg += b_ih[512+eg] + b_hh[512+eg];
    go += b_ih[768+eg] + b_hh[768+eg];
    if (L0) {
      float x0 = obs[(size_t)bg*16 + t*2], x1 = obs[(size_t)bg*16 + t*2 + 1];
      gi += x0*w_ih[2*eg]         + x1*w_ih[2*eg+1];
      gf += x0*w_ih[2*(256+eg)]   + x1*w_ih[2*(256+eg)+1];
      gg += x0*w_ih[2*(512+eg)]   + x1*w_ih[2*(512+eg)+1];
      go += x0*w_ih[2*(768+eg)]   + x1*w_ih[2*(768+eg)+1];
    }
    float iv = sigm(gi), fv = sigm(gf), gv = tanhf(gg), ov = sigm(go);
    size_t off = (size_t)bg*256 + eg;
    float cn = HH ? (fv * c[off] + iv * gv) : (iv * gv);
    float hn = ov * tanhf(cn);
    c[off] = cn; h[off] = hn;
  }
}

// ---------------------------------------------------------------------------
// Fused per-mode stack. Block: 64 rows of one mode. A-tiles live in LDS.
// mpass: out[64 x 32*CPT] = act(A[64x256] @ W[:,koff:koff+256]^T + bias)
template<int CPT, int ACT, bool STORE>
__device__ __forceinline__ void mpass(const float (*A)[LDP], float (*O)[LDP],
    const float* __restrict__ W, int wstride, int wkoff,
    const float* __restrict__ bias, float* acc, float (*Bs)[BST], int tid)
{
  const int trow = tid >> 5, tcol = tid & 31;
  const int c0 = tcol * CPT;
  const int p0 = c0 + ((c0 >> 5) << 3);      // bank-group swizzle
  for (int kb = 0; kb < 256; kb += 16) {
    if (CPT == 8) {
      int cS = tid >> 1, ko = (tid & 1) * 8;
      const float* src = W + (size_t)cS * wstride + wkoff + kb + ko;
      f4 v0 = *(const f4*)src;
      f4 v1 = *(const f4*)(src + 4);
      int p = cS + ((cS >> 5) << 3);
      Bs[ko+0][p]=v0.x; Bs[ko+1][p]=v0.y; Bs[ko+2][p]=v0.z; Bs[ko+3][p]=v0.w;
      Bs[ko+4][p]=v1.x; Bs[ko+5][p]=v1.y; Bs[ko+6][p]=v1.z; Bs[ko+7][p]=v1.w;
    } else {  // CPT==4, width 128
      int cS = tid >> 2, ko = (tid & 3) * 4;
      const float* src = W + (size_t)cS * wstride + wkoff + kb + ko;
      f4 v0 = *(const f4*)src;
      int p = cS + ((cS >> 5) << 3);
      Bs[ko+0][p]=v0.x; Bs[ko+1][p]=v0.y; Bs[ko+2][p]=v0.z; Bs[ko+3][p]=v0.w;
    }
    __syncthreads();
#pragma unroll
    for (int k4 = 0; k4 < 4; ++k4) {
      float aw[4][4];
#pragma unroll
      for (int i = 0; i < 4; ++i) {
        f4 tv = *(const f4*)&A[trow*4+i][kb + k4*4];
        aw[i][0]=tv.x; aw[i][1]=tv.y; aw[i][2]=tv.z; aw[i][3]=tv.w;
      }
#pragma unroll
      for (int kk = 0; kk < 4; ++kk) {
        const float* bp = &Bs[k4*4+kk][p0];
        f4 b0 = *(const f4*)bp;
        if (CPT == 8) {
          f4 b1 = *(const f4*)(bp + 4);
#pragma unroll
          for (int i = 0; i < 4; ++i) {
            float av = aw[i][kk];
            acc[i*8+0]+=av*b0.x; acc[i*8+1]+=av*b0.y; acc[i*8+2]+=av*b0.z; acc[i*8+3]+=av*b0.w;
            acc[i*8+4]+=av*b1.x; acc[i*8+5]+=av*b1.y; acc[i*8+6]+=av*b1.z; acc[i*8+7]+=av*b1.w;
          }
        } else {
#pragma unroll
          for (int i = 0; i < 4; ++i) {
            float av = aw[i][kk];
            acc[i*4+0]+=av*b0.x; acc[i*4+1]+=av*b0.y; acc[i*4+2]+=av*b0.z; acc[i*4+3]+=av*b0.w;
          }
        }
      }
    }
    __syncthreads();
  }
  if (STORE) {
#pragma unroll
    for (int i = 0; i < 4; ++i) {
      int r = trow*4 + i;
#pragma unroll
      for (int jj = 0; jj < CPT; jj += 4) {
        int cc = c0 + jj;
        f4 bv = *(const f4*)&bias[cc];
        f4 o;
        o.x = acc[i*CPT+jj+0] + bv.x;
        o.y = acc[i*CPT+jj+1] + bv.y;
        o.z = acc[i*CPT+jj+2] + bv.z;
        o.w = acc[i*CPT+jj+3] + bv.w;
        if (ACT == 1) { o.x=fmaxf(o.x,0.f); o.y=fmaxf(o.y,0.f); o.z=fmaxf(o.z,0.f); o.w=fmaxf(o.w,0.f); }
        else if (ACT == 2) { o.x=eluf(o.x); o.y=eluf(o.y); o.z=eluf(o.z); o.w=eluf(o.w); }
        *(f4*)&O[r][cc] = o;
      }
    }
  }
}

__device__ __forceinline__ void lnpass(const float (*In)[LDP], float (*Out)[LDP],
    const float* __restrict__ g, const float* __restrict__ b, int tid)
{
  __syncthreads();
  const int row = tid >> 3, seg = tid & 7;
  float s = 0.f, ss = 0.f;
#pragma unroll
  for (int q = 0; q < 8; ++q) {
    f4 v = *(const f4*)&In[row][seg*32 + q*4];
    s  += v.x + v.y + v.z + v.w;
    ss += v.x*v.x + v.y*v.y + v.z*v.z + v.w*v.w;
  }
#pragma unroll
  for (int d = 1; d < 8; d <<= 1) { s += __shfl_xor(s, d); ss += __shfl_xor(ss, d); }
  float mean = s * (1.f/256.f);
  float var  = ss * (1.f/256.f) - mean*mean;
  float rs = rsqrtf(var + 1e-5f);
#pragma unroll
  for (int q = 0; q < 8; ++q) {
    int cc = seg*32 + q*4;
    f4 v = *(const f4*)&In[row][cc];
    f4 gv = *(const f4*)&g[cc];
    f4 bv = *(const f4*)&b[cc];
    f4 o;
    o.x = (v.x-mean)*rs*gv.x + bv.x;
    o.y = (v.y-mean)*rs*gv.y + bv.y;
    o.z = (v.z-mean)*rs*gv.z + bv.z;
    o.w = (v.w-mean)*rs*gv.w + bv.w;
    *(f4*)&Out[row][cc] = o;
  }
  __syncthreads();
}

// deltas += D[64x256-chunk] @ dec_w2[:, koff:koff+256]^T  (24 cols padded to 32)
__device__ __forceinline__ void dec2pass(const float (*A)[LDP], const float* __restrict__ W,
    int wkoff, float* dacc, float (*Bs)[BST], int tid)
{
  const int row = tid >> 3, cb = (tid & 7) * 4;
  for (int kb = 0; kb < 256; kb += 16) {
    if (tid < 128) {
      int cS = tid >> 2, ko = (tid & 3) * 4;
      f4 v = make_float4(0.f, 0.f, 0.f, 0.f);
      if (cS < 24) v = *(const f4*)(W + (size_t)cS * 512 + wkoff + kb + ko);
      Bs[ko+0][cS]=v.x; Bs[ko+1][cS]=v.y; Bs[ko+2][cS]=v.z; Bs[ko+3][cS]=v.w;
    }
    __syncthreads();
#pragma unroll
    for (int k4 = 0; k4 < 4; ++k4) {
      f4 a = *(const f4*)&A[row][kb + k4*4];
      float av[4] = {a.x, a.y, a.z, a.w};
#pragma unroll
      for (int kk = 0; kk < 4; ++kk) {
        f4 bv = *(const f4*)&Bs[k4*4+kk][cb];
        dacc[0]+=av[kk]*bv.x; dacc[1]+=av[kk]*bv.y; dacc[2]+=av[kk]*bv.z; dacc[3]+=av[kk]*bv.w;
      }
    }
    __syncthreads();
  }
}

__global__ __launch_bounds__(512, 2)
void mode_stack(const float* __restrict__ emb, const float* __restrict__ W2c,
  const float* __restrict__ b2c,
  const float* __restrict__ ln1_g, const float* __restrict__ ln1_b,
  const float* __restrict__ ffn_w1, const float* __restrict__ ffn_b1,
  const float* __restrict__ ffn_w2, const float* __restrict__ ffn_b2,
  const float* __restrict__ ln2_g, const float* __restrict__ ln2_b,
  const float* __restrict__ dec_w1, const float* __restrict__ dec_b1,
  const float* __restrict__ dec_w2, const float* __restrict__ dec_b2,
  const float* __restrict__ sc_w1, const float* __restrict__ sc_b1,
  const float* __restrict__ sc_w2, const float* __restrict__ sc_b2,
  const float* __restrict__ obs, float* __restrict__ pred, float* __restrict__ score)
{
  __shared__ float Xs[64][LDP];
  __shared__ float Ys[64][LDP];
  __shared__ float Bs[16][BST];
  const int tid = threadIdx.x;
  const int r0 = blockIdx.x * 64;
  const int m  = blockIdx.y;

#pragma unroll
  for (int it = 0; it < 8; ++it) {
    int idx = tid + it*512;
    int row = idx >> 6, col = (idx & 63) * 4;
    *(f4*)&Xs[row][col] = *(const f4*)(emb + (size_t)(r0+row)*256 + col);
  }
  {
    float acc[32];
#pragma unroll
    for (int z = 0; z < 32; ++z) acc[z] = 0.f;
    mpass<8,0,true>(Xs, Ys, W2c + (size_t)m*65536, 256, 0, b2c + m*256, acc, Bs, tid);
  }
  lnpass(Ys, Xs, ln1_g, ln1_b, tid);              // Xs = h1
  float h2a[32];
#pragma unroll
  for (int z = 0; z < 32; ++z) h2a[z] = 0.f;
  for (int c4 = 0; c4 < 4; ++c4) {
    float tacc[32];
#pragma unroll
    for (int z = 0; z < 32; ++z) tacc[z] = 0.f;
    mpass<8,1,true>(Xs, Ys, ffn_w1 + (size_t)c4*256*256, 256, 0, ffn_b1 + c4*256, tacc, Bs, tid);
    mpass<8,0,false>(Ys, Xs /*unused*/, ffn_w2, 1024, c4*256, nullptr, h2a, Bs, tid);
  }
  {
    const int trow = tid >> 5, tcol = tid & 31;
#pragma unroll
    for (int i = 0; i < 4; ++i) {
#pragma unroll
      for (int jj = 0; jj < 8; jj += 4) {
        int cc = tcol*8 + jj;
        f4 bv = *(const f4*)&ffn_b2[cc];
        f4 o;
        o.x = h2a[i*8+jj+0] + bv.x;
        o.y = h2a[i*8+jj+1] + bv.y;
        o.z = h2a[i*8+jj+2] + bv.z;
        o.w = h2a[i*8+jj+3] + bv.w;
        *(f4*)&Ys[trow*4+i][cc] = o;
      }
    }
  }
  lnpass(Ys, Xs, ln2_g, ln2_b, tid);              // Xs = mm_emb
  float dacc[4] = {0.f, 0.f, 0.f, 0.f};
  for (int c2 = 0; c2 < 2; ++c2) {
    float tacc[32];
#pragma unroll
    for (int z = 0; z < 32; ++z) tacc[z] = 0.f;
    mpass<8,2,true>(Xs, Ys, dec_w1 + (size_t)c2*256*256, 256, 0, dec_b1 + c2*256, tacc, Bs, tid);
    dec2pass(Ys, dec_w2, c2*256, dacc, Bs, tid);
  }
  {
    float sacc[16];
#pragma unroll
    for (int z = 0; z < 16; ++z) sacc[z] = 0.f;
    mpass<4,2,true>(Xs, Ys, sc_w1, 256, 0, sc_b1, sacc, Bs, tid);
  }
  __syncthreads();
  if (tid < 64) {
    float s = sc_b2[0];
#pragma unroll
    for (int k = 0; k < 128; k += 4) {
      f4 a = *(const f4*)&Ys[tid][k];
      f4 w = *(const f4*)&sc_w2[k];
      s += a.x*w.x + a.y*w.y + a.z*w.z + a.w*w.w;
    }
    score[(size_t)(r0+tid)*20 + m] = s;
  }
  {
    const int row = tid >> 3, cb = (tid & 7) * 4;
    if (cb < 24) {
      f4 bv = *(const f4*)&dec_b2[cb];
      float lp0 = obs[(size_t)(r0+row)*16 + 14];
      float lp1 = obs[(size_t)(r0+row)*16 + 15];
      f4 o;
      o.x = dacc[0] + bv.x + lp0;
      o.y = dacc[1] + bv.y + lp1;
      o.z = dacc[2] + bv.z + lp0;
      o.w = dacc[3] + bv.w + lp1;
      *(f4*)&pred[((size_t)(r0+row)*20 + m)*24 + cb] = o;
    }
  }
}

// ---------------------------------------------------------------------------
extern "C" void kernel_launch(void* const* d_in, const int* in_sizes, int n_in,
                              void* d_out, int out_size, void* d_ws, size_t ws_size,
                              hipStream_t stream)
{
  (void)in_sizes; (void)n_in; (void)out_size; (void)ws_size;
  const float* obs    = (const float*)d_in[0];
  const float* w_ih0  = (const float*)d_in[1];
  const float* w_hh0  = (const float*)d_in[2];
  const float* b_ih0  = (const float*)d_in[3];
  const float* b_hh0  = (const float*)d_in[4];
  const float* w_ih1  = (const float*)d_in[5];
  const float* w_hh1  = (const float*)d_in[6];
  const float* b_ih1  = (const float*)d_in[7];
  const float* b_hh1  = (const float*)d_in[8];
  const float* ipw    = (const float*)d_in[9];
  const float* ipb    = (const float*)d_in[10];
  const float* out_w  = (const float*)d_in[11];
  const float* out_b  = (const float*)d_in[12];
  const float* ln1_g  = (const float*)d_in[13];
  const float* ln1_b  = (const float*)d_in[14];
  const float* ffn_w1 = (const float*)d_in[15];
  const float* ffn_b1 = (const float*)d_in[16];
  const float* ffn_w2 = (const float*)d_in[17];
  const float* ffn_b2 = (const float*)d_in[18];
  const float* ln2_g  = (const float*)d_in[19];
  const float* ln2_b  = (const float*)d_in[20];
  const float* dec_w1 = (const float*)d_in[21];
  const float* dec_b1 = (const float*)d_in[22];
  const float* dec_w2 = (const float*)d_in[23];
  const float* dec_b2 = (const float*)d_in[24];
  const float* sc_w1  = (const float*)d_in[25];
  const float* sc_b1  = (const float*)d_in[26];
  const float* sc_w2  = (const float*)d_in[27];
  const float* sc_b2  = (const float*)d_in[28];

  float* outp   = (float*)d_out;
  float* pred   = outp;
  float* scoreo = outp + (size_t)8192*20*24;

  float* ws = (float*)d_ws;
  const size_t SB = (size_t)8192*256;
  float* h0[2] = { ws,          ws + SB };
  float* c0    = ws + 2*SB;
  float* h1[2] = { ws + 3*SB,   ws + 4*SB };
  float* c1    = ws + 5*SB;
  float* W2c   = ws + 6*SB;                   // 20*65536 floats
  float* b2cp  = W2c + (size_t)20*65536;      // 5120 floats

  w2c_kernel<<<dim3(16,20), 256, 0, stream>>>(out_w, ipw, W2c);
  b2c_kernel<<<20, 256, 0, stream>>>(out_w, out_b, ipb, b2cp);

  dim3 lg(128, 8);
  for (int t = 0; t < 8; ++t) {
    int ri = t & 1, wi = ri ^ 1;
    if (t == 0) {
      lstm_step<false,false,true ><<<lg,512,0,stream>>>(nullptr, nullptr, w_ih0, w_hh0, b_ih0, b_hh0, obs, t, h0[wi], c0);
      lstm_step<true, false,false><<<lg,512,0,stream>>>(h0[wi],  nullptr, w_ih1, w_hh1, b_ih1, b_hh1, obs, t, h1[wi], c1);
    } else {
      lstm_step<false,true, true ><<<lg,512,0,stream>>>(nullptr, h0[ri],  w_ih0, w_hh0, b_ih0, b_hh0, obs, t, h0[wi], c0);
      lstm_step<true, true, false><<<lg,512,0,stream>>>(h0[wi],  h1[ri],  w_ih1, w_hh1, b_ih1, b_hh1, obs, t, h1[wi], c1);
    }
  }
  // t=7 wrote h1[0] => emb
  mode_stack<<<dim3(128,20), 512, 0, stream>>>(h1[0], W2c, b2cp,
      ln1_g, ln1_b, ffn_w1, ffn_b1, ffn_w2, ffn_b2, ln2_g, ln2_b,
      dec_w1, dec_b1, dec_w2, dec_b2, sc_w1, sc_b1, sc_w2, sc_b2,
      obs, pred, scoreo);
}

// Round 2
// 5885.734 us; speedup vs baseline: 1.2346x; 1.2346x over previous
//
#include <hip/hip_runtime.h>
#include <math.h>

// PredictorNoEgo: B=8192 T=8 E=256 M=20 FS=12
// Algebraic facts: softmax over size-1 axis == 1 => ctx == v (q,k dead);
// attn_out = emb @ (out_w[m] @ Wv[m])^T + (out_w[m]@bv[m] + out_b[m])
//
// R1 fix: all inner-loop LDS reads are now either full-wave contiguous
// (64 lanes x consecutive f4 = 1KB row) or wave-uniform broadcast.
#define LDP 260   // activation tile stride (260 % 32 == 4 spreads row-strided reads)
#define BSP 260   // B-tile stride

typedef float4 f4;

__device__ __forceinline__ float sigm(float x){ return 1.0f/(1.0f + __expf(-x)); }
__device__ __forceinline__ float eluf(float x){ return x > 0.f ? x : expm1f(x); }

// ---------------------------------------------------------------------------
// W2c[m] = out_w[m] (256x256) @ in_proj_w[m,512:768,:] (256x256)  (unchanged)
__global__ __launch_bounds__(256, 4)
void w2c_kernel(const float* __restrict__ out_w, const float* __restrict__ ipw,
                float* __restrict__ W2c)
{
  __shared__ float As[16][68];
  __shared__ float Bs2[16][68];
  const int tid = threadIdx.x;
  const int m = blockIdx.y;
  const int o0 = (blockIdx.x >> 2) * 64, e0 = (blockIdx.x & 3) * 64;
  const int trow = tid >> 4, tcol = tid & 15;
  const float* Ap = out_w + (size_t)m * 65536;
  const float* Bp = ipw + ((size_t)m * 768 + 512) * 256;
  float acc[16];
#pragma unroll
  for (int z = 0; z < 16; ++z) acc[z] = 0.f;
  for (int kb = 0; kb < 256; kb += 16) {
    { int row = tid >> 2, ko = (tid & 3) * 4;
      f4 v = *(const f4*)(Ap + (size_t)(o0+row)*256 + kb + ko);
      As[ko+0][row]=v.x; As[ko+1][row]=v.y; As[ko+2][row]=v.z; As[ko+3][row]=v.w; }
    { int k = tid >> 4, eo = (tid & 15) * 4;
      *(f4*)&Bs2[k][eo] = *(const f4*)(Bp + (size_t)(kb+k)*256 + e0 + eo); }
    __syncthreads();
#pragma unroll
    for (int k = 0; k < 16; ++k) {
      f4 a4 = *(const f4*)&As[k][trow*4];
      f4 b4 = *(const f4*)&Bs2[k][tcol*4];
      acc[0]+=a4.x*b4.x; acc[1]+=a4.x*b4.y; acc[2]+=a4.x*b4.z; acc[3]+=a4.x*b4.w;
      acc[4]+=a4.y*b4.x; acc[5]+=a4.y*b4.y; acc[6]+=a4.y*b4.z; acc[7]+=a4.y*b4.w;
      acc[8]+=a4.z*b4.x; acc[9]+=a4.z*b4.y; acc[10]+=a4.z*b4.z; acc[11]+=a4.z*b4.w;
      acc[12]+=a4.w*b4.x; acc[13]+=a4.w*b4.y; acc[14]+=a4.w*b4.z; acc[15]+=a4.w*b4.w;
    }
    __syncthreads();
  }
#pragma unroll
  for (int i = 0; i < 4; ++i)
    *(f4*)&W2c[((size_t)m*256 + o0 + trow*4 + i)*256 + e0 + tcol*4] =
        make_float4(acc[i*4+0], acc[i*4+1], acc[i*4+2], acc[i*4+3]);
}

__global__ void b2c_kernel(const float* __restrict__ out_w, const float* __restrict__ out_b,
                           const float* __restrict__ ipb, float* __restrict__ b2c)
{
  __shared__ float pb[256];
  const int m = blockIdx.x, o = threadIdx.x;
  pb[o] = ipb[(size_t)m*768 + 512 + o];
  __syncthreads();
  const float* wr = out_w + ((size_t)m*256 + o)*256;
  float acc = out_b[(size_t)m*256 + o];
  for (int f = 0; f < 256; f += 4) {
    f4 w = *(const f4*)&wr[f];
    acc += w.x*pb[f] + w.y*pb[f+1] + w.z*pb[f+2] + w.w*pb[f+3];
  }
  b2c[(size_t)m*256 + o] = acc;
}

// ---------------------------------------------------------------------------
// LSTM step. Block: 256 thr (4 waves), tile 32 rows x 256 gate-cols where
// col c: gate = c>>6, e = e0 + (c&63).  grid (256, 4).  3 blocks/CU.
template<bool IH, bool HH, bool L0>
__global__ __launch_bounds__(256, 3)
void lstm_step(const float* __restrict__ a_ih, const float* __restrict__ a_hh,
               const float* __restrict__ w_ih, const float* __restrict__ w_hh,
               const float* __restrict__ b_ih, const float* __restrict__ b_hh,
               const float* __restrict__ obs, int t,
               float* __restrict__ h, float* __restrict__ c)
{
  __shared__ float As[16][36];     // k-major A tile (32 rows)
  __shared__ float Bs[16][BSP];    // k-major B tile (256 gate-cols)
  __shared__ float Gs[32][LDP];    // gate staging
  const int tid = threadIdx.x;
  const int lane = tid & 63, wv = tid >> 6;
  const int r0 = blockIdx.x * 32, e0 = blockIdx.y * 64;
  const int rw = wv * 8;           // wave's 8 rows
  const int c0 = lane * 4;         // lane's 4 cols (within one gate)
  float acc[32];
#pragma unroll
  for (int z = 0; z < 32; ++z) acc[z] = 0.f;

  const int bjr = ((tid >> 6) << 8) + e0 + (tid & 63);  // W row for col=tid

  auto gphase = [&](const float* __restrict__ Ag, const float* __restrict__ Wg){
    const float* wr = Wg + (size_t)bjr * 256;
    for (int kb = 0; kb < 256; kb += 16) {
      if (tid < 128) {
        int row = tid >> 2, ko = (tid & 3) * 4;
        f4 v = *(const f4*)(Ag + (size_t)(r0+row)*256 + kb + ko);
        As[ko+0][row]=v.x; As[ko+1][row]=v.y; As[ko+2][row]=v.z; As[ko+3][row]=v.w;
      }
      {
        f4 v0 = *(const f4*)(wr + kb);
        f4 v1 = *(const f4*)(wr + kb + 4);
        f4 v2 = *(const f4*)(wr + kb + 8);
        f4 v3 = *(const f4*)(wr + kb + 12);
        Bs[0][tid]=v0.x;  Bs[1][tid]=v0.y;  Bs[2][tid]=v0.z;  Bs[3][tid]=v0.w;
        Bs[4][tid]=v1.x;  Bs[5][tid]=v1.y;  Bs[6][tid]=v1.z;  Bs[7][tid]=v1.w;
        Bs[8][tid]=v2.x;  Bs[9][tid]=v2.y;  Bs[10][tid]=v2.z; Bs[11][tid]=v2.w;
        Bs[12][tid]=v3.x; Bs[13][tid]=v3.y; Bs[14][tid]=v3.z; Bs[15][tid]=v3.w;
      }
      __syncthreads();
#pragma unroll
      for (int k = 0; k < 16; ++k) {
        f4 b  = *(const f4*)&Bs[k][c0];       // contiguous 1KB across wave
        f4 a0 = *(const f4*)&As[k][rw];       // wave-uniform broadcast
        f4 a1 = *(const f4*)&As[k][rw+4];
        float ar[8] = {a0.x,a0.y,a0.z,a0.w,a1.x,a1.y,a1.z,a1.w};
#pragma unroll
        for (int i = 0; i < 8; ++i) {
          acc[i*4+0] += ar[i]*b.x;
          acc[i*4+1] += ar[i]*b.y;
          acc[i*4+2] += ar[i]*b.z;
          acc[i*4+3] += ar[i]*b.w;
        }
      }
      __syncthreads();
    }
  };
  if (IH) gphase(a_ih, w_ih);
  if (HH) gphase(a_hh, w_hh);

#pragma unroll
  for (int i = 0; i < 8; ++i)
    *(f4*)&Gs[rw+i][c0] = make_float4(acc[i*4],acc[i*4+1],acc[i*4+2],acc[i*4+3]);
  __syncthreads();

  {
    const int row = tid >> 3, eb = (tid & 7) * 8;
    const int eg0 = e0 + eb;
    float gv[4][8];
#pragma unroll
    for (int g = 0; g < 4; ++g) {
      f4 u0 = *(const f4*)&Gs[row][g*64 + eb];
      f4 u1 = *(const f4*)&Gs[row][g*64 + eb + 4];
      f4 bi0 = *(const f4*)&b_ih[g*256 + eg0];
      f4 bi1 = *(const f4*)&b_ih[g*256 + eg0 + 4];
      f4 bh0 = *(const f4*)&b_hh[g*256 + eg0];
      f4 bh1 = *(const f4*)&b_hh[g*256 + eg0 + 4];
      gv[g][0]=u0.x+bi0.x+bh0.x; gv[g][1]=u0.y+bi0.y+bh0.y;
      gv[g][2]=u0.z+bi0.z+bh0.z; gv[g][3]=u0.w+bi0.w+bh0.w;
      gv[g][4]=u1.x+bi1.x+bh1.x; gv[g][5]=u1.y+bi1.y+bh1.y;
      gv[g][6]=u1.z+bi1.z+bh1.z; gv[g][7]=u1.w+bi1.w+bh1.w;
    }
    if (L0) {
      const int bg = r0 + row;
      float x0 = obs[(size_t)bg*16 + t*2], x1 = obs[(size_t)bg*16 + t*2 + 1];
#pragma unroll
      for (int g = 0; g < 4; ++g) {
        const float* wp = w_ih + (size_t)(g*256 + eg0)*2;
        f4 w0 = *(const f4*)(wp);
        f4 w1 = *(const f4*)(wp+4);
        f4 w2 = *(const f4*)(wp+8);
        f4 w3 = *(const f4*)(wp+12);
        gv[g][0] += x0*w0.x + x1*w0.y;  gv[g][1] += x0*w0.z + x1*w0.w;
        gv[g][2] += x0*w1.x + x1*w1.y;  gv[g][3] += x0*w1.z + x1*w1.w;
        gv[g][4] += x0*w2.x + x1*w2.y;  gv[g][5] += x0*w2.z + x1*w2.w;
        gv[g][6] += x0*w3.x + x1*w3.y;  gv[g][7] += x0*w3.z + x1*w3.w;
      }
    }
    const size_t off = (size_t)(r0+row)*256 + eg0;
    float cv[8], hv[8];
    if (HH) {
      f4 cp0 = *(const f4*)&c[off];
      f4 cp1 = *(const f4*)&c[off+4];
      float cold[8] = {cp0.x,cp0.y,cp0.z,cp0.w,cp1.x,cp1.y,cp1.z,cp1.w};
#pragma unroll
      for (int j = 0; j < 8; ++j) {
        float cn = sigm(gv[1][j])*cold[j] + sigm(gv[0][j])*tanhf(gv[2][j]);
        cv[j] = cn; hv[j] = sigm(gv[3][j])*tanhf(cn);
      }
    } else {
#pragma unroll
      for (int j = 0; j < 8; ++j) {
        float cn = sigm(gv[0][j])*tanhf(gv[2][j]);
        cv[j] = cn; hv[j] = sigm(gv[3][j])*tanhf(cn);
      }
    }
    *(f4*)&c[off]   = make_float4(cv[0],cv[1],cv[2],cv[3]);
    *(f4*)&c[off+4] = make_float4(cv[4],cv[5],cv[6],cv[7]);
    *(f4*)&h[off]   = make_float4(hv[0],hv[1],hv[2],hv[3]);
    *(f4*)&h[off+4] = make_float4(hv[4],hv[5],hv[6],hv[7]);
  }
}

// ---------------------------------------------------------------------------
// Fused per-mode stack.  Block 512 thr (8 waves), 64 rows of one mode.
// Thread tile: 8 rows x 4 cols; cols = lane*4 (contiguous across wave).
template<int ACT, bool STORE>
__device__ __forceinline__ void mpass256(const float (*A)[LDP], float (*O)[LDP],
    const float* __restrict__ W, int wstride, int wkoff,
    const float* __restrict__ bias, float* acc, float (*Bs)[BSP], int tid)
{
  const int lane = tid & 63, wv = tid >> 6;
  const int rw = wv * 8;
  const int c0 = lane * 4;
  const int bc = tid >> 1, bkh = (tid & 1) * 8;
  const float* wr = W + (size_t)bc * wstride + wkoff + bkh;
  f4 p0 = *(const f4*)(wr);
  f4 p1 = *(const f4*)(wr + 4);
  for (int kb = 0; kb < 256; kb += 16) {
    Bs[bkh+0][bc]=p0.x; Bs[bkh+1][bc]=p0.y; Bs[bkh+2][bc]=p0.z; Bs[bkh+3][bc]=p0.w;
    Bs[bkh+4][bc]=p1.x; Bs[bkh+5][bc]=p1.y; Bs[bkh+6][bc]=p1.z; Bs[bkh+7][bc]=p1.w;
    __syncthreads();
    if (kb + 16 < 256) {                       // prefetch next tile across barrier
      p0 = *(const f4*)(wr + kb + 16);
      p1 = *(const f4*)(wr + kb + 20);
    }
#pragma unroll
    for (int k4 = 0; k4 < 4; ++k4) {
      f4 b0 = *(const f4*)&Bs[k4*4+0][c0];     // contiguous 1KB across wave
      f4 b1 = *(const f4*)&Bs[k4*4+1][c0];
      f4 b2 = *(const f4*)&Bs[k4*4+2][c0];
      f4 b3 = *(const f4*)&Bs[k4*4+3][c0];
#pragma unroll
      for (int i = 0; i < 8; ++i) {
        f4 a = *(const f4*)&A[rw+i][kb + k4*4];  // wave-uniform broadcast
        acc[i*4+0] += a.x*b0.x + a.y*b1.x + a.z*b2.x + a.w*b3.x;
        acc[i*4+1] += a.x*b0.y + a.y*b1.y + a.z*b2.y + a.w*b3.y;
        acc[i*4+2] += a.x*b0.z + a.y*b1.z + a.z*b2.z + a.w*b3.z;
        acc[i*4+3] += a.x*b0.w + a.y*b1.w + a.z*b2.w + a.w*b3.w;
      }
    }
    __syncthreads();
  }
  if (STORE) {
    f4 bv = *(const f4*)&bias[c0];
#pragma unroll
    for (int i = 0; i < 8; ++i) {
      f4 o;
      o.x = acc[i*4+0] + bv.x; o.y = acc[i*4+1] + bv.y;
      o.z = acc[i*4+2] + bv.z; o.w = acc[i*4+3] + bv.w;
      if (ACT == 1) { o.x=fmaxf(o.x,0.f); o.y=fmaxf(o.y,0.f); o.z=fmaxf(o.z,0.f); o.w=fmaxf(o.w,0.f); }
      else if (ACT == 2) { o.x=eluf(o.x); o.y=eluf(o.y); o.z=eluf(o.z); o.w=eluf(o.w); }
      *(f4*)&O[rw+i][c0] = o;   // contiguous row store
    }
  }
}

// LayerNorm: wave-per-row, full-wave shuffle reduce (conflict-free).
__device__ __forceinline__ void lnpass(const float (*In)[LDP], float (*Out)[LDP],
    const float* __restrict__ g, const float* __restrict__ b, int tid)
{
  __syncthreads();
  const int lane = tid & 63, wv = tid >> 6;
  const int c0 = lane * 4;
  f4 gv = *(const f4*)&g[c0];
  f4 bv = *(const f4*)&b[c0];
#pragma unroll
  for (int i = 0; i < 8; ++i) {
    const int r = wv*8 + i;
    f4 v = *(const f4*)&In[r][c0];
    float s  = v.x + v.y + v.z + v.w;
    float ss = v.x*v.x + v.y*v.y + v.z*v.z + v.w*v.w;
#pragma unroll
    for (int d = 1; d < 64; d <<= 1) { s += __shfl_xor(s, d); ss += __shfl_xor(ss, d); }
    float mean = s * (1.f/256.f);
    float var  = ss * (1.f/256.f) - mean*mean;
    float rs = rsqrtf(var + 1e-5f);
    f4 o;
    o.x = (v.x-mean)*rs*gv.x + bv.x;
    o.y = (v.y-mean)*rs*gv.y + bv.y;
    o.z = (v.z-mean)*rs*gv.z + bv.z;
    o.w = (v.w-mean)*rs*gv.w + bv.w;
    *(f4*)&Out[r][c0] = o;
  }
  __syncthreads();
}

// deltas += D[64 x 256-chunk] @ dec_w2[:, koff:koff+256]^T (24 cols pad to 32)
__device__ __forceinline__ void dec2pass(const float (*A)[LDP], const float* __restrict__ W,
    int wkoff, float* dacc, float (*Bs)[BSP], int tid)
{
  const int row = tid >> 3, cb = (tid & 7) * 4;
  for (int kb = 0; kb < 256; kb += 16) {
    if (tid < 128) {
      int cS = tid >> 2, ko = (tid & 3) * 4;
      f4 v = make_float4(0.f, 0.f, 0.f, 0.f);
      if (cS < 24) v = *(const f4*)(W + (size_t)cS * 512 + wkoff + kb + ko);
      Bs[ko+0][cS]=v.x; Bs[ko+1][cS]=v.y; Bs[ko+2][cS]=v.z; Bs[ko+3][cS]=v.w;
    }
    __syncthreads();
#pragma unroll
    for (int k4 = 0; k4 < 4; ++k4) {
      f4 a = *(const f4*)&A[row][kb + k4*4];   // 8 rows/wave, LDP=260 spreads banks
      float av[4] = {a.x, a.y, a.z, a.w};
#pragma unroll
      for (int kk = 0; kk < 4; ++kk) {
        f4 bv = *(const f4*)&Bs[k4*4+kk][cb];  // 8 addrs, 8-lane broadcast each
        dacc[0]+=av[kk]*bv.x; dacc[1]+=av[kk]*bv.y; dacc[2]+=av[kk]*bv.z; dacc[3]+=av[kk]*bv.w;
      }
    }
    __syncthreads();
  }
}

// score head: 64x128 GEMM, thread tile 8 rows x 2 cols (b64 contiguous reads)
__device__ __forceinline__ void scpass(const float (*A)[LDP],
    const float* __restrict__ W, float* acc, float (*Bs)[BSP], int tid)
{
  const int lane = tid & 63, wv = tid >> 6;
  const int rw = wv * 8;
  const int c0 = lane * 2;
  const int bc = tid >> 2, bk = (tid & 3) * 4;
  const float* wr = W + (size_t)bc * 256 + bk;
  for (int kb = 0; kb < 256; kb += 16) {
    f4 v = *(const f4*)(wr + kb);
    Bs[bk+0][bc]=v.x; Bs[bk+1][bc]=v.y; Bs[bk+2][bc]=v.z; Bs[bk+3][bc]=v.w;
    __syncthreads();
#pragma unroll
    for (int k4 = 0; k4 < 4; ++k4) {
      float2 b0 = *(const float2*)&Bs[k4*4+0][c0];
      float2 b1 = *(const float2*)&Bs[k4*4+1][c0];
      float2 b2 = *(const float2*)&Bs[k4*4+2][c0];
      float2 b3 = *(const float2*)&Bs[k4*4+3][c0];
#pragma unroll
      for (int i = 0; i < 8; ++i) {
        f4 a = *(const f4*)&A[rw+i][kb + k4*4];
        acc[i*2+0] += a.x*b0.x + a.y*b1.x + a.z*b2.x + a.w*b3.x;
        acc[i*2+1] += a.x*b0.y + a.y*b1.y + a.z*b2.y + a.w*b3.y;
      }
    }
    __syncthreads();
  }
}

__global__ __launch_bounds__(512, 2)
void mode_stack(const float* __restrict__ emb, const float* __restrict__ W2c,
  const float* __restrict__ b2c,
  const float* __restrict__ ln1_g, const float* __restrict__ ln1_b,
  const float* __restrict__ ffn_w1, const float* __restrict__ ffn_b1,
  const float* __restrict__ ffn_w2, const float* __restrict__ ffn_b2,
  const float* __restrict__ ln2_g, const float* __restrict__ ln2_b,
  const float* __restrict__ dec_w1, const float* __restrict__ dec_b1,
  const float* __restrict__ dec_w2, const float* __restrict__ dec_b2,
  const float* __restrict__ sc_w1, const float* __restrict__ sc_b1,
  const float* __restrict__ sc_w2, const float* __restrict__ sc_b2,
  const float* __restrict__ obs, float* __restrict__ pred, float* __restrict__ score)
{
  __shared__ float Xs[64][LDP];
  __shared__ float Ys[64][LDP];
  __shared__ float Bs[16][BSP];
  const int tid = threadIdx.x;
  const int lane = tid & 63, wv = tid >> 6;
  const int r0 = blockIdx.x * 64;
  const int m  = blockIdx.y;
  const int rw = wv * 8, c0 = lane * 4;

#pragma unroll
  for (int it = 0; it < 8; ++it) {
    int idx = tid + it*512;
    int row = idx >> 6;
    *(f4*)&Xs[row][c0] = *(const f4*)(emb + (size_t)(r0+row)*256 + c0);
  }
  {
    float acc[32];
#pragma unroll
    for (int z = 0; z < 32; ++z) acc[z] = 0.f;
    mpass256<0,true>(Xs, Ys, W2c + (size_t)m*65536, 256, 0, b2c + m*256, acc, Bs, tid);
  }
  lnpass(Ys, Xs, ln1_g, ln1_b, tid);              // Xs = h1
  float h2a[32];
#pragma unroll
  for (int z = 0; z < 32; ++z) h2a[z] = 0.f;
  for (int c4 = 0; c4 < 4; ++c4) {
    float tacc[32];
#pragma unroll
    for (int z = 0; z < 32; ++z) tacc[z] = 0.f;
    mpass256<1,true>(Xs, Ys, ffn_w1 + (size_t)c4*65536, 256, 0, ffn_b1 + c4*256, tacc, Bs, tid);
    mpass256<0,false>(Ys, Xs /*unused*/, ffn_w2, 1024, c4*256, nullptr, h2a, Bs, tid);
  }
  {
    f4 bv = *(const f4*)&ffn_b2[c0];
#pragma unroll
    for (int i = 0; i < 8; ++i) {
      f4 o;
      o.x = h2a[i*4+0] + bv.x; o.y = h2a[i*4+1] + bv.y;
      o.z = h2a[i*4+2] + bv.z; o.w = h2a[i*4+3] + bv.w;
      *(f4*)&Ys[rw+i][c0] = o;
    }
  }
  lnpass(Ys, Xs, ln2_g, ln2_b, tid);              // Xs = mm_emb
  float dacc[4] = {0.f, 0.f, 0.f, 0.f};
  for (int c2 = 0; c2 < 2; ++c2) {
    float tacc[32];
#pragma unroll
    for (int z = 0; z < 32; ++z) tacc[z] = 0.f;
    mpass256<2,true>(Xs, Ys, dec_w1 + (size_t)c2*65536, 256, 0, dec_b1 + c2*256, tacc, Bs, tid);
    dec2pass(Ys, dec_w2, c2*256, dacc, Bs, tid);
  }
  {
    float sacc[16];
#pragma unroll
    for (int z = 0; z < 16; ++z) sacc[z] = 0.f;
    scpass(Xs, sc_w1, sacc, Bs, tid);
    float2 sb  = *(const float2*)&sc_b1[lane*2];
    float2 w2v = *(const float2*)&sc_w2[lane*2];
    float scb2 = sc_b2[0];
#pragma unroll
    for (int i = 0; i < 8; ++i) {
      float e0v = eluf(sacc[i*2+0] + sb.x);
      float e1v = eluf(sacc[i*2+1] + sb.y);
      float part = e0v*w2v.x + e1v*w2v.y;
#pragma unroll
      for (int d = 1; d < 64; d <<= 1) part += __shfl_xor(part, d);
      if (lane == 0) score[(size_t)(r0 + rw + i)*20 + m] = part + scb2;
    }
  }
  {
    const int row = tid >> 3, cb = (tid & 7) * 4;
    if (cb < 24) {
      f4 bv = *(const f4*)&dec_b2[cb];
      float lp0 = obs[(size_t)(r0+row)*16 + 14];
      float lp1 = obs[(size_t)(r0+row)*16 + 15];
      f4 o;
      o.x = dacc[0] + bv.x + lp0;
      o.y = dacc[1] + bv.y + lp1;
      o.z = dacc[2] + bv.z + lp0;
      o.w = dacc[3] + bv.w + lp1;
      *(f4*)&pred[((size_t)(r0+row)*20 + m)*24 + cb] = o;
    }
  }
}

// ---------------------------------------------------------------------------
extern "C" void kernel_launch(void* const* d_in, const int* in_sizes, int n_in,
                              void* d_out, int out_size, void* d_ws, size_t ws_size,
                              hipStream_t stream)
{
  (void)in_sizes; (void)n_in; (void)out_size; (void)ws_size;
  const float* obs    = (const float*)d_in[0];
  const float* w_ih0  = (const float*)d_in[1];
  const float* w_hh0  = (const float*)d_in[2];
  const float* b_ih0  = (const float*)d_in[3];
  const float* b_hh0  = (const float*)d_in[4];
  const float* w_ih1  = (const float*)d_in[5];
  const float* w_hh1  = (const float*)d_in[6];
  const float* b_ih1  = (const float*)d_in[7];
  const float* b_hh1  = (const float*)d_in[8];
  const float* ipw    = (const float*)d_in[9];
  const float* ipb    = (const float*)d_in[10];
  const float* out_w  = (const float*)d_in[11];
  const float* out_b  = (const float*)d_in[12];
  const float* ln1_g  = (const float*)d_in[13];
  const float* ln1_b  = (const float*)d_in[14];
  const float* ffn_w1 = (const float*)d_in[15];
  const float* ffn_b1 = (const float*)d_in[16];
  const float* ffn_w2 = (const float*)d_in[17];
  const float* ffn_b2 = (const float*)d_in[18];
  const float* ln2_g  = (const float*)d_in[19];
  const float* ln2_b  = (const float*)d_in[20];
  const float* dec_w1 = (const float*)d_in[21];
  const float* dec_b1 = (const float*)d_in[22];
  const float* dec_w2 = (const float*)d_in[23];
  const float* dec_b2 = (const float*)d_in[24];
  const float* sc_w1  = (const float*)d_in[25];
  const float* sc_b1  = (const float*)d_in[26];
  const float* sc_w2  = (const float*)d_in[27];
  const float* sc_b2  = (const float*)d_in[28];

  float* outp   = (float*)d_out;
  float* pred   = outp;
  float* scoreo = outp + (size_t)8192*20*24;

  float* ws = (float*)d_ws;
  const size_t SB = (size_t)8192*256;
  float* h0[2] = { ws,          ws + SB };
  float* c0    = ws + 2*SB;
  float* h1[2] = { ws + 3*SB,   ws + 4*SB };
  float* c1    = ws + 5*SB;
  float* W2c   = ws + 6*SB;                   // 20*65536 floats
  float* b2cp  = W2c + (size_t)20*65536;      // 5120 floats

  w2c_kernel<<<dim3(16,20), 256, 0, stream>>>(out_w, ipw, W2c);
  b2c_kernel<<<20, 256, 0, stream>>>(out_w, out_b, ipb, b2cp);

  dim3 lg(256, 4);
  for (int t = 0; t < 8; ++t) {
    int ri = t & 1, wi = ri ^ 1;
    if (t == 0) {
      lstm_step<false,false,true ><<<lg,256,0,stream>>>(nullptr, nullptr, w_ih0, w_hh0, b_ih0, b_hh0, obs, t, h0[wi], c0);
      lstm_step<true, false,false><<<lg,256,0,stream>>>(h0[wi],  nullptr, w_ih1, w_hh1, b_ih1, b_hh1, obs, t, h1[wi], c1);
    } else {
      lstm_step<false,true, true ><<<lg,256,0,stream>>>(nullptr, h0[ri],  w_ih0, w_hh0, b_ih0, b_hh0, obs, t, h0[wi], c0);
      lstm_step<true, true, false><<<lg,256,0,stream>>>(h0[wi],  h1[ri],  w_ih1, w_hh1, b_ih1, b_hh1, obs, t, h1[wi], c1);
    }
  }
  // t=7 wrote h1[0] => emb
  mode_stack<<<dim3(128,20), 512, 0, stream>>>(h1[0], W2c, b2cp,
      ln1_g, ln1_b, ffn_w1, ffn_b1, ffn_w2, ffn_b2, ln2_g, ln2_b,
      dec_w1, dec_b1, dec_w2, dec_b2, sc_w1, sc_b1, sc_w2, sc_b2,
      obs, pred, scoreo);
}

// Round 3
// 972.880 us; speedup vs baseline: 7.4689x; 6.0498x over previous
//
#include <hip/hip_runtime.h>
#include <math.h>

// PredictorNoEgo: B=8192 T=8 E=256 M=20 FS=12
// Algebra: softmax over size-1 axis == 1 => ctx == v (q,k dead);
//          attn_out = emb @ (out_w[m] @ Wv[m])^T + (out_w[m]@bv[m] + out_b[m])
// R3: all GEMMs on bf16 MFMA (v_mfma_f32_32x32x16_bf16), fp32 accum/bias/LN/cell.
// Weights pre-converted once per launch to fragment-linear bf16 (1KB chunks,
// perfectly coalesced 16B/lane loads from L2; no LDS staging for B).

typedef float4 f4;
typedef unsigned int u32;
typedef unsigned short u16;
typedef __attribute__((ext_vector_type(16))) float f32x16;
typedef __attribute__((ext_vector_type(8)))  short s16x8;

__device__ __forceinline__ float sigm(float x){ return 1.0f/(1.0f + __expf(-x)); }
__device__ __forceinline__ float tanhfast(float x){ return 2.0f*sigm(2.0f*x) - 1.0f; }
__device__ __forceinline__ float eluf(float x){ return x > 0.f ? x : expm1f(x); }
__device__ __forceinline__ u16 f2bf(float x){
  u32 u = __float_as_uint(x);
  return (u16)((u + 0x7FFFu + ((u>>16)&1u)) >> 16);
}
__device__ __forceinline__ float bf2f(u16 h){ return __uint_as_float(((u32)h)<<16); }

// MFMA 32x32x16 bf16 layout (m74/m101 verified):
//  A-frag lane l: A[row=l&31][k=(l>>5)*8+j]   B-frag lane l: B[k=(l>>5)*8+j][col=l&31]
//  C/D reg r:     row=(r&3)+8*(r>>2)+4*(l>>5), col=l&31
// Fragment-linear W' for row-major W[C][K]: chunk=(ct*(K/16)+ks), elem ((chunk)*64+l)*8+j
//  holds W[ct*32+(l&31)][ks*16+(l>>5)*8+j].

#define LSTR 264  // LDS row stride (u16 elems) = 528B = 33*16B: aligned, bank-balanced

// ---------------------------------------------------------------------------
// W2c[m] = out_w[m] (256x256) @ in_proj_w[m,512:768,:] (256x256)   (fp32)
__global__ __launch_bounds__(256, 4)
void w2c_kernel(const float* __restrict__ out_w, const float* __restrict__ ipw,
                float* __restrict__ W2c)
{
  __shared__ float As[16][68];
  __shared__ float Bs2[16][68];
  const int tid = threadIdx.x;
  const int m = blockIdx.y;
  const int o0 = (blockIdx.x >> 2) * 64, e0 = (blockIdx.x & 3) * 64;
  const int trow = tid >> 4, tcol = tid & 15;
  const float* Ap = out_w + (size_t)m * 65536;
  const float* Bp = ipw + ((size_t)m * 768 + 512) * 256;
  float acc[16];
#pragma unroll
  for (int z = 0; z < 16; ++z) acc[z] = 0.f;
  for (int kb = 0; kb < 256; kb += 16) {
    { int row = tid >> 2, ko = (tid & 3) * 4;
      f4 v = *(const f4*)(Ap + (size_t)(o0+row)*256 + kb + ko);
      As[ko+0][row]=v.x; As[ko+1][row]=v.y; As[ko+2][row]=v.z; As[ko+3][row]=v.w; }
    { int k = tid >> 4, eo = (tid & 15) * 4;
      *(f4*)&Bs2[k][eo] = *(const f4*)(Bp + (size_t)(kb+k)*256 + e0 + eo); }
    __syncthreads();
#pragma unroll
    for (int k = 0; k < 16; ++k) {
      f4 a4 = *(const f4*)&As[k][trow*4];
      f4 b4 = *(const f4*)&Bs2[k][tcol*4];
      acc[0]+=a4.x*b4.x; acc[1]+=a4.x*b4.y; acc[2]+=a4.x*b4.z; acc[3]+=a4.x*b4.w;
      acc[4]+=a4.y*b4.x; acc[5]+=a4.y*b4.y; acc[6]+=a4.y*b4.z; acc[7]+=a4.y*b4.w;
      acc[8]+=a4.z*b4.x; acc[9]+=a4.z*b4.y; acc[10]+=a4.z*b4.z; acc[11]+=a4.z*b4.w;
      acc[12]+=a4.w*b4.x; acc[13]+=a4.w*b4.y; acc[14]+=a4.w*b4.z; acc[15]+=a4.w*b4.w;
    }
    __syncthreads();
  }
#pragma unroll
  for (int i = 0; i < 4; ++i)
    *(f4*)&W2c[((size_t)m*256 + o0 + trow*4 + i)*256 + e0 + tcol*4] =
        make_float4(acc[i*4+0], acc[i*4+1], acc[i*4+2], acc[i*4+3]);
}

// b2c[m,o] = out_b[m,o] + sum_f out_w[m,o,f]*in_proj_b[m,512+f]
__global__ void b2c_kernel(const float* __restrict__ out_w, const float* __restrict__ out_b,
                           const float* __restrict__ ipb, float* __restrict__ b2c)
{
  __shared__ float pb[256];
  const int m = blockIdx.x, o = threadIdx.x;
  pb[o] = ipb[(size_t)m*768 + 512 + o];
  __syncthreads();
  const float* wr = out_w + ((size_t)m*256 + o)*256;
  float acc = out_b[(size_t)m*256 + o];
  for (int f = 0; f < 256; f += 4) {
    f4 w = *(const f4*)&wr[f];
    acc += w.x*pb[f] + w.y*pb[f+1] + w.z*pb[f+2] + w.w*pb[f+3];
  }
  b2c[(size_t)m*256 + o] = acc;
}

// ---------------------------------------------------------------------------
// Convert f32 row-major [C][K] -> fragment-linear bf16 (C padded up to mult of 32)
__device__ __forceinline__ void cvt_seg(const float* __restrict__ src, u16* __restrict__ dst,
                                        int Creal, int lognks, int g)
{
  const int l = g & 63;
  const int cks = g >> 6;
  const int ks = cks & ((1 << lognks) - 1);
  const int ct = cks >> lognks;
  const int c = ct*32 + (l & 31);
  const int K = 16 << lognks;
  const int k = ks*16 + ((l >> 5) * 8);
  s16x8 r;
  if (c < Creal) {
    const float* s = src + (size_t)c * K + k;
    f4 v0 = *(const f4*)s;
    f4 v1 = *(const f4*)(s + 4);
    r[0]=(short)f2bf(v0.x); r[1]=(short)f2bf(v0.y); r[2]=(short)f2bf(v0.z); r[3]=(short)f2bf(v0.w);
    r[4]=(short)f2bf(v1.x); r[5]=(short)f2bf(v1.y); r[6]=(short)f2bf(v1.z); r[7]=(short)f2bf(v1.w);
  } else {
#pragma unroll
    for (int j = 0; j < 8; ++j) r[j] = 0;
  }
  *(s16x8*)(dst + (size_t)g * 8) = r;
}

__global__ __launch_bounds__(256)
void wcvt_all(const float* __restrict__ whh0, const float* __restrict__ wih1,
              const float* __restrict__ whh1, const float* __restrict__ W2c,
              const float* __restrict__ ffn1, const float* __restrict__ ffn2,
              const float* __restrict__ dec1, const float* __restrict__ dec2,
              const float* __restrict__ sc1,  u16* __restrict__ dst)
{
  int g = blockIdx.x * 256 + threadIdx.x;
  if      (g <  32768) cvt_seg(whh0, dst + 0,       1024, 4, g);
  else if (g <  65536) cvt_seg(wih1, dst + 262144,  1024, 4, g - 32768);
  else if (g <  98304) cvt_seg(whh1, dst + 524288,  1024, 4, g - 65536);
  else if (g < 262144) cvt_seg(W2c,  dst + 786432,  5120, 4, g - 98304);
  else if (g < 294912) cvt_seg(ffn1, dst + 2097152, 1024, 4, g - 262144);
  else if (g < 327680) cvt_seg(ffn2, dst + 2359296,  256, 6, g - 294912);
  else if (g < 344064) cvt_seg(dec1, dst + 2621440,  512, 4, g - 327680);
  else if (g < 346112) cvt_seg(dec2, dst + 2752512,   24, 5, g - 344064);
  else if (g < 350208) cvt_seg(sc1,  dst + 2768896,  128, 4, g - 346112);
}

// ---------------------------------------------------------------------------
// Fused LSTM: 256 blocks x 32 rows, 4 waves. h bf16 in LDS, c fp32 in regs.
__device__ __forceinline__ void zero_acc8(f32x16 acc[4][2]){
  f32x16 z;
#pragma unroll
  for (int i = 0; i < 16; ++i) z[i] = 0.f;
#pragma unroll
  for (int g = 0; g < 4; ++g)
#pragma unroll
    for (int e = 0; e < 2; ++e) acc[g][e] = z;
}

__device__ __forceinline__ void gemm_h(f32x16 acc[4][2], const u16* As, const u16* __restrict__ Bf,
                                       int w, int lane)
{
  const int col = lane & 31, hi = lane >> 5;
#pragma unroll 2
  for (int ks = 0; ks < 16; ++ks) {
    s16x8 a = *(const s16x8*)(As + col*LSTR + ks*16 + hi*8);
#pragma unroll
    for (int g = 0; g < 4; ++g)
#pragma unroll
      for (int ei = 0; ei < 2; ++ei) {
        const int ct = g*8 + 2*w + ei;
        s16x8 b = *(const s16x8*)(Bf + ((size_t)(ct*16 + ks)*64 + lane)*8);
        acc[g][ei] = __builtin_amdgcn_mfma_f32_32x32x16_bf16(a, b, acc[g][ei], 0, 0, 0);
      }
  }
}

__global__ __launch_bounds__(256)
void lstm_fused(const u16* __restrict__ whh0f, const u16* __restrict__ wih1f,
                const u16* __restrict__ whh1f, const float* __restrict__ w_ih0,
                const float* __restrict__ b_ih0, const float* __restrict__ b_hh0,
                const float* __restrict__ b_ih1, const float* __restrict__ b_hh1,
                const float* __restrict__ obs, u16* __restrict__ emb)
{
  __shared__ u16 h0s[32 * LSTR];
  __shared__ u16 h1s[32 * LSTR];
  __shared__ float obs_s[512];
  const int tid = threadIdx.x;
  const int lane = tid & 63, w = tid >> 6;
  const int col = lane & 31, hi = lane >> 5;
  const int r0 = blockIdx.x * 32;
  for (int i = tid; i < 512; i += 256) obs_s[i] = obs[(size_t)r0 * 16 + i];

  float bs0[4][2], bs1[4][2], xw0[4][2], xw1[4][2];
#pragma unroll
  for (int g = 0; g < 4; ++g)
#pragma unroll
    for (int ei = 0; ei < 2; ++ei) {
      const int cg = g*256 + (2*w + ei)*32 + col;
      bs0[g][ei] = b_ih0[cg] + b_hh0[cg];
      bs1[g][ei] = b_ih1[cg] + b_hh1[cg];
      xw0[g][ei] = w_ih0[2*cg];
      xw1[g][ei] = w_ih0[2*cg + 1];
    }
  float c0v[2][16], c1v[2][16];
#pragma unroll
  for (int ei = 0; ei < 2; ++ei)
#pragma unroll
    for (int r = 0; r < 16; ++r) { c0v[ei][r] = 0.f; c1v[ei][r] = 0.f; }

  f32x16 acc[4][2];
  __syncthreads();

  for (int t = 0; t < 8; ++t) {
    // ----- layer 0
    zero_acc8(acc);
    if (t > 0) gemm_h(acc, h0s, whh0f, w, lane);
    __syncthreads();
#pragma unroll
    for (int ei = 0; ei < 2; ++ei) {
      const int e = (2*w + ei)*32 + col;
#pragma unroll
      for (int r = 0; r < 16; ++r) {
        const int row = (r&3) + 8*(r>>2) + 4*hi;
        float x0 = obs_s[row*16 + 2*t], x1 = obs_s[row*16 + 2*t + 1];
        float gi = acc[0][ei][r] + bs0[0][ei] + x0*xw0[0][ei] + x1*xw1[0][ei];
        float gf = acc[1][ei][r] + bs0[1][ei] + x0*xw0[1][ei] + x1*xw1[1][ei];
        float gg = acc[2][ei][r] + bs0[2][ei] + x0*xw0[2][ei] + x1*xw1[2][ei];
        float go = acc[3][ei][r] + bs0[3][ei] + x0*xw0[3][ei] + x1*xw1[3][ei];
        float cn = sigm(gf)*c0v[ei][r] + sigm(gi)*tanhfast(gg);
        c0v[ei][r] = cn;
        h0s[row*LSTR + e] = f2bf(sigm(go)*tanhfast(cn));
      }
    }
    __syncthreads();
    // ----- layer 1
    zero_acc8(acc);
    gemm_h(acc, h0s, wih1f, w, lane);
    if (t > 0) gemm_h(acc, h1s, whh1f, w, lane);
    __syncthreads();
#pragma unroll
    for (int ei = 0; ei < 2; ++ei) {
      const int e = (2*w + ei)*32 + col;
#pragma unroll
      for (int r = 0; r < 16; ++r) {
        const int row = (r&3) + 8*(r>>2) + 4*hi;
        float gi = acc[0][ei][r] + bs1[0][ei];
        float gf = acc[1][ei][r] + bs1[1][ei];
        float gg = acc[2][ei][r] + bs1[2][ei];
        float go = acc[3][ei][r] + bs1[3][ei];
        float cn = sigm(gf)*c1v[ei][r] + sigm(gi)*tanhfast(gg);
        c1v[ei][r] = cn;
        h1s[row*LSTR + e] = f2bf(sigm(go)*tanhfast(cn));
      }
    }
    __syncthreads();
  }
  // emb = h1[7]
#pragma unroll
  for (int kk = 0; kk < 4; ++kk) {
    const int gi2 = tid + kk*256;
    const int row = gi2 >> 5, grp = gi2 & 31;
    *(s16x8*)(emb + (size_t)(r0 + row)*256 + grp*8) = *(const s16x8*)(h1s + row*LSTR + grp*8);
  }
}

// ---------------------------------------------------------------------------
// mode_stack: 512 thr (8 waves), 64 rows x one mode. grid (128, 20).
__device__ __forceinline__ void gemm256(const u16* As, const u16* __restrict__ Bf,
                                        f32x16 acc[2], int w, int lane)
{
  const int col = lane & 31, hi = lane >> 5;
#pragma unroll 4
  for (int ks = 0; ks < 16; ++ks) {
    s16x8 b  = *(const s16x8*)(Bf + ((size_t)(w*16 + ks)*64 + lane)*8);
    s16x8 a0 = *(const s16x8*)(As + col*LSTR + ks*16 + hi*8);
    s16x8 a1 = *(const s16x8*)(As + (32 + col)*LSTR + ks*16 + hi*8);
    acc[0] = __builtin_amdgcn_mfma_f32_32x32x16_bf16(a0, b, acc[0], 0, 0, 0);
    acc[1] = __builtin_amdgcn_mfma_f32_32x32x16_bf16(a1, b, acc[1], 0, 0, 0);
  }
}

__device__ __forceinline__ void gemm_ffn2(const u16* As, const u16* __restrict__ Bf,
                                          f32x16 acc[2], int c4, int w, int lane)
{
  const int col = lane & 31, hi = lane >> 5;
#pragma unroll 4
  for (int ks = 0; ks < 16; ++ks) {
    s16x8 b  = *(const s16x8*)(Bf + ((size_t)(w*64 + c4*16 + ks)*64 + lane)*8);
    s16x8 a0 = *(const s16x8*)(As + col*LSTR + ks*16 + hi*8);
    s16x8 a1 = *(const s16x8*)(As + (32 + col)*LSTR + ks*16 + hi*8);
    acc[0] = __builtin_amdgcn_mfma_f32_32x32x16_bf16(a0, b, acc[0], 0, 0, 0);
    acc[1] = __builtin_amdgcn_mfma_f32_32x32x16_bf16(a1, b, acc[1], 0, 0, 0);
  }
}

__device__ __forceinline__ void gemm_dec2(const u16* As, const u16* __restrict__ Bf,
                                          f32x16 acc[2], int c2, int lane)
{
  const int col = lane & 31, hi = lane >> 5;
#pragma unroll 4
  for (int ks = 0; ks < 16; ++ks) {
    s16x8 b  = *(const s16x8*)(Bf + ((size_t)(c2*16 + ks)*64 + lane)*8);
    s16x8 a0 = *(const s16x8*)(As + col*LSTR + ks*16 + hi*8);
    s16x8 a1 = *(const s16x8*)(As + (32 + col)*LSTR + ks*16 + hi*8);
    acc[0] = __builtin_amdgcn_mfma_f32_32x32x16_bf16(a0, b, acc[0], 0, 0, 0);
    acc[1] = __builtin_amdgcn_mfma_f32_32x32x16_bf16(a1, b, acc[1], 0, 0, 0);
  }
}

// epilogue: acc + bias, activation, -> bf16 LDS tile. ACT: 0 none, 1 relu, 2 elu
template<int ACT>
__device__ __forceinline__ void epi_store(f32x16 acc[2], const float* __restrict__ bias,
                                          u16* Ys, int w, int lane)
{
  const int col = lane & 31, hi = lane >> 5, cg = w*32 + col;
  const float bv = bias[cg];
#pragma unroll
  for (int rt = 0; rt < 2; ++rt)
#pragma unroll
    for (int r = 0; r < 16; ++r) {
      float v = acc[rt][r] + bv;
      if (ACT == 1) v = fmaxf(v, 0.f);
      else if (ACT == 2) v = eluf(v);
      const int row = rt*32 + (r&3) + 8*(r>>2) + 4*hi;
      Ys[row*LSTR + cg] = f2bf(v);
    }
}

__device__ __forceinline__ void lnpass_bf(const u16* In, u16* Out,
    const float* __restrict__ g, const float* __restrict__ b, int tid)
{
  const int lane = tid & 63, w = tid >> 6;
  f4 gv = *(const f4*)&g[lane*4];
  f4 bv = *(const f4*)&b[lane*4];
#pragma unroll
  for (int i = 0; i < 8; ++i) {
    const int row = w*8 + i;
    ushort4 uv = *(const ushort4*)(In + row*LSTR + lane*4);
    float v0 = bf2f(uv.x), v1 = bf2f(uv.y), v2 = bf2f(uv.z), v3 = bf2f(uv.w);
    float s  = v0 + v1 + v2 + v3;
    float ss = v0*v0 + v1*v1 + v2*v2 + v3*v3;
#pragma unroll
    for (int d = 1; d < 64; d <<= 1) { s += __shfl_xor(s, d); ss += __shfl_xor(ss, d); }
    const float mean = s * (1.f/256.f);
    const float rs = rsqrtf(ss * (1.f/256.f) - mean*mean + 1e-5f);
    ushort4 o;
    o.x = f2bf((v0 - mean)*rs*gv.x + bv.x);
    o.y = f2bf((v1 - mean)*rs*gv.y + bv.y);
    o.z = f2bf((v2 - mean)*rs*gv.z + bv.z);
    o.w = f2bf((v3 - mean)*rs*gv.w + bv.w);
    *(ushort4*)(Out + row*LSTR + lane*4) = o;
  }
}

__global__ __launch_bounds__(512, 4)
void mode_stack(const u16* __restrict__ emb, const u16* __restrict__ W2cf,
  const float* __restrict__ b2c,
  const float* __restrict__ ln1_g, const float* __restrict__ ln1_b,
  const u16* __restrict__ ffn1f, const float* __restrict__ ffn_b1,
  const u16* __restrict__ ffn2f, const float* __restrict__ ffn_b2,
  const float* __restrict__ ln2_g, const float* __restrict__ ln2_b,
  const u16* __restrict__ dec1f, const float* __restrict__ dec_b1,
  const u16* __restrict__ dec2f, const float* __restrict__ dec_b2,
  const u16* __restrict__ sc1f,  const float* __restrict__ sc_b1,
  const float* __restrict__ sc_w2, const float* __restrict__ sc_b2,
  const float* __restrict__ obs, float* __restrict__ pred, float* __restrict__ score)
{
  __shared__ u16 Xs[64 * LSTR];
  __shared__ u16 Ys[64 * LSTR];
  __shared__ float obs_ls[128];
  const int tid = threadIdx.x;
  const int lane = tid & 63, w = tid >> 6;
  const int col = lane & 31, hi = lane >> 5;
  const int r0 = blockIdx.x * 64;
  const int m  = blockIdx.y;

  f32x16 za;
#pragma unroll
  for (int i = 0; i < 16; ++i) za[i] = 0.f;

#pragma unroll
  for (int kk = 0; kk < 4; ++kk) {
    const int gi2 = tid + kk*512;
    const int row = gi2 >> 5, grp = gi2 & 31;
    *(s16x8*)(Xs + row*LSTR + grp*8) = *(const s16x8*)(emb + (size_t)(r0 + row)*256 + grp*8);
  }
  if (tid < 128) obs_ls[tid] = obs[(size_t)(r0 + (tid >> 1))*16 + 14 + (tid & 1)];
  __syncthreads();

  { // attn-out (fused v-proj + out-proj)
    f32x16 acc[2]; acc[0] = za; acc[1] = za;
    gemm256(Xs, W2cf + (size_t)m*65536, acc, w, lane);
    epi_store<0>(acc, b2c + m*256, Ys, w, lane);
  }
  __syncthreads();
  lnpass_bf(Ys, Xs, ln1_g, ln1_b, tid);   // Xs = h1
  __syncthreads();

  f32x16 h2[2]; h2[0] = za; h2[1] = za;
  for (int c4 = 0; c4 < 4; ++c4) {
    f32x16 tacc[2]; tacc[0] = za; tacc[1] = za;
    gemm256(Xs, ffn1f + (size_t)c4*65536, tacc, w, lane);
    epi_store<1>(tacc, ffn_b1 + c4*256, Ys, w, lane);
    __syncthreads();
    gemm_ffn2(Ys, ffn2f, h2, c4, w, lane);
    __syncthreads();
  }
  epi_store<0>(h2, ffn_b2, Ys, w, lane);
  __syncthreads();
  lnpass_bf(Ys, Xs, ln2_g, ln2_b, tid);   // Xs = mm_emb
  __syncthreads();

  f32x16 dv[2]; dv[0] = za; dv[1] = za;
  for (int c2 = 0; c2 < 2; ++c2) {
    f32x16 tacc[2]; tacc[0] = za; tacc[1] = za;
    gemm256(Xs, dec1f + (size_t)c2*65536, tacc, w, lane);
    epi_store<2>(tacc, dec_b1 + c2*256, Ys, w, lane);
    __syncthreads();
    if (w == 0) gemm_dec2(Ys, dec2f, dv, c2, lane);
    __syncthreads();
  }

  if (w < 4) { // score head layer 1 (128 cols)
    f32x16 sacc[2]; sacc[0] = za; sacc[1] = za;
    gemm256(Xs, sc1f, sacc, w, lane);
    epi_store<2>(sacc, sc_b1, Ys, w, lane);
  }
  __syncthreads();
  { // score head layer 2: dot(128) per row
    const float scb2 = sc_b2[0];
    const float2 w2v = *(const float2*)&sc_w2[lane*2];
#pragma unroll
    for (int i = 0; i < 8; ++i) {
      const int row = w*8 + i;
      u32 pv = *(const u32*)(Ys + row*LSTR + lane*2);
      float part = bf2f((u16)(pv & 0xFFFF))*w2v.x + bf2f((u16)(pv >> 16))*w2v.y;
#pragma unroll
      for (int d = 1; d < 64; d <<= 1) part += __shfl_xor(part, d);
      if (lane == 0) score[(size_t)(r0 + row)*20 + m] = part + scb2;
    }
  }
  // predictions epilogue (deltas + last_pos)
  if (w == 0 && col < 24) {
    const float db = dec_b2[col];
#pragma unroll
    for (int rt = 0; rt < 2; ++rt)
#pragma unroll
      for (int r = 0; r < 16; ++r) {
        const int row = rt*32 + (r&3) + 8*(r>>2) + 4*hi;
        const float lp = obs_ls[row*2 + (col & 1)];
        pred[((size_t)(r0 + row)*20 + m)*24 + col] = dv[rt][r] + db + lp;
      }
  }
}

// ---------------------------------------------------------------------------
extern "C" void kernel_launch(void* const* d_in, const int* in_sizes, int n_in,
                              void* d_out, int out_size, void* d_ws, size_t ws_size,
                              hipStream_t stream)
{
  (void)in_sizes; (void)n_in; (void)out_size; (void)ws_size;
  const float* obs    = (const float*)d_in[0];
  const float* w_ih0  = (const float*)d_in[1];
  const float* w_hh0  = (const float*)d_in[2];
  const float* b_ih0  = (const float*)d_in[3];
  const float* b_hh0  = (const float*)d_in[4];
  const float* w_ih1  = (const float*)d_in[5];
  const float* w_hh1  = (const float*)d_in[6];
  const float* b_ih1  = (const float*)d_in[7];
  const float* b_hh1  = (const float*)d_in[8];
  const float* ipw    = (const float*)d_in[9];
  const float* ipb    = (const float*)d_in[10];
  const float* out_w  = (const float*)d_in[11];
  const float* out_b  = (const float*)d_in[12];
  const float* ln1_g  = (const float*)d_in[13];
  const float* ln1_b  = (const float*)d_in[14];
  const float* ffn_w1 = (const float*)d_in[15];
  const float* ffn_b1 = (const float*)d_in[16];
  const float* ffn_w2 = (const float*)d_in[17];
  const float* ffn_b2 = (const float*)d_in[18];
  const float* ln2_g  = (const float*)d_in[19];
  const float* ln2_b  = (const float*)d_in[20];
  const float* dec_w1 = (const float*)d_in[21];
  const float* dec_b1 = (const float*)d_in[22];
  const float* dec_w2 = (const float*)d_in[23];
  const float* dec_b2 = (const float*)d_in[24];
  const float* sc_w1  = (const float*)d_in[25];
  const float* sc_b1  = (const float*)d_in[26];
  const float* sc_w2  = (const float*)d_in[27];
  const float* sc_b2  = (const float*)d_in[28];

  float* outp   = (float*)d_out;
  float* pred   = outp;
  float* scoreo = outp + (size_t)8192*20*24;

  // workspace layout
  float* wsf   = (float*)d_ws;
  float* W2c   = wsf;                         // 1310720 f32
  float* b2cp  = wsf + 1310720;               // 5120 f32
  u16*   wsh   = (u16*)(wsf + 1315840);       // 16B-aligned
  u16* whh0f = wsh + 0;
  u16* wih1f = wsh + 262144;
  u16* whh1f = wsh + 524288;
  u16* W2cf  = wsh + 786432;
  u16* ffn1f = wsh + 2097152;
  u16* ffn2f = wsh + 2359296;
  u16* dec1f = wsh + 2621440;
  u16* dec2f = wsh + 2752512;
  u16* sc1f  = wsh + 2768896;
  u16* emb   = wsh + 2801664;                 // 8192*256 bf16

  w2c_kernel<<<dim3(16, 20), 256, 0, stream>>>(out_w, ipw, W2c);
  b2c_kernel<<<20, 256, 0, stream>>>(out_w, out_b, ipb, b2cp);
  wcvt_all<<<1368, 256, 0, stream>>>(w_hh0, w_ih1, w_hh1, W2c, ffn_w1, ffn_w2,
                                     dec_w1, dec_w2, sc_w1, wsh);
  lstm_fused<<<256, 256, 0, stream>>>(whh0f, wih1f, whh1f, w_ih0, b_ih0, b_hh0,
                                      b_ih1, b_hh1, obs, emb);
  mode_stack<<<dim3(128, 20), 512, 0, stream>>>(emb, W2cf, b2cp,
      ln1_g, ln1_b, ffn1f, ffn_b1, ffn2f, ffn_b2, ln2_g, ln2_b,
      dec1f, dec_b1, dec2f, dec_b2, sc1f, sc_b1, sc_w2, sc_b2,
      obs, pred, scoreo);
}

// Round 4
// 847.950 us; speedup vs baseline: 8.5693x; 1.1473x over previous
//
#include <hip/hip_runtime.h>
#include <math.h>

// PredictorNoEgo: B=8192 T=8 E=256 M=20 FS=12
// Algebra: softmax over size-1 axis == 1 => ctx == v (q,k dead);
//          attn_out = emb @ (out_w[m] @ Wv[m])^T + (out_w[m]@bv[m] + out_b[m])
// R4: latency-hiding restructure. lstm: 8 waves, dual recurrence GEMMs in
// phase1 (8 indep chains). mode_stack: 128 rows/block, 4 MFMA per B-load.

typedef float4 f4;
typedef unsigned int u32;
typedef unsigned short u16;
typedef __attribute__((ext_vector_type(16))) float f32x16;
typedef __attribute__((ext_vector_type(8)))  short s16x8;

__device__ __forceinline__ float sigm(float x){ return 1.0f/(1.0f + __expf(-x)); }
__device__ __forceinline__ float tanhfast(float x){ return 2.0f*sigm(2.0f*x) - 1.0f; }
__device__ __forceinline__ float eluf(float x){ return x > 0.f ? x : expm1f(x); }
__device__ __forceinline__ u16 f2bf(float x){
  u32 u = __float_as_uint(x);
  return (u16)((u + 0x7FFFu + ((u>>16)&1u)) >> 16);
}
__device__ __forceinline__ float bf2f(u16 h){ return __uint_as_float(((u32)h)<<16); }

// MFMA 32x32x16 bf16: A lane l: A[row=l&31][k=(l>>5)*8+j]; B lane l: B[k][col=l&31]
// C/D reg r: row=(r&3)+8*(r>>2)+4*(l>>5), col=l&31
// Fragment-linear W' (row-major W[C][K]): elem ((ct*(K/16)+ks)*64+l)*8+j
//   = W[ct*32+(l&31)][ks*16+(l>>5)*8+j]

#define LSTR 264  // LDS row stride in u16 (528B): 16B-aligned, bank-balanced

// ---------------------------------------------------------------------------
// W2c[m] = out_w[m] (256x256) @ in_proj_w[m,512:768,:] (256x256)   (fp32)
__global__ __launch_bounds__(256, 4)
void w2c_kernel(const float* __restrict__ out_w, const float* __restrict__ ipw,
                float* __restrict__ W2c)
{
  __shared__ float As[16][68];
  __shared__ float Bs2[16][68];
  const int tid = threadIdx.x;
  const int m = blockIdx.y;
  const int o0 = (blockIdx.x >> 2) * 64, e0 = (blockIdx.x & 3) * 64;
  const int trow = tid >> 4, tcol = tid & 15;
  const float* Ap = out_w + (size_t)m * 65536;
  const float* Bp = ipw + ((size_t)m * 768 + 512) * 256;
  float acc[16];
#pragma unroll
  for (int z = 0; z < 16; ++z) acc[z] = 0.f;
  for (int kb = 0; kb < 256; kb += 16) {
    { int row = tid >> 2, ko = (tid & 3) * 4;
      f4 v = *(const f4*)(Ap + (size_t)(o0+row)*256 + kb + ko);
      As[ko+0][row]=v.x; As[ko+1][row]=v.y; As[ko+2][row]=v.z; As[ko+3][row]=v.w; }
    { int k = tid >> 4, eo = (tid & 15) * 4;
      *(f4*)&Bs2[k][eo] = *(const f4*)(Bp + (size_t)(kb+k)*256 + e0 + eo); }
    __syncthreads();
#pragma unroll
    for (int k = 0; k < 16; ++k) {
      f4 a4 = *(const f4*)&As[k][trow*4];
      f4 b4 = *(const f4*)&Bs2[k][tcol*4];
      acc[0]+=a4.x*b4.x; acc[1]+=a4.x*b4.y; acc[2]+=a4.x*b4.z; acc[3]+=a4.x*b4.w;
      acc[4]+=a4.y*b4.x; acc[5]+=a4.y*b4.y; acc[6]+=a4.y*b4.z; acc[7]+=a4.y*b4.w;
      acc[8]+=a4.z*b4.x; acc[9]+=a4.z*b4.y; acc[10]+=a4.z*b4.z; acc[11]+=a4.z*b4.w;
      acc[12]+=a4.w*b4.x; acc[13]+=a4.w*b4.y; acc[14]+=a4.w*b4.z; acc[15]+=a4.w*b4.w;
    }
    __syncthreads();
  }
#pragma unroll
  for (int i = 0; i < 4; ++i)
    *(f4*)&W2c[((size_t)m*256 + o0 + trow*4 + i)*256 + e0 + tcol*4] =
        make_float4(acc[i*4+0], acc[i*4+1], acc[i*4+2], acc[i*4+3]);
}

__global__ void b2c_kernel(const float* __restrict__ out_w, const float* __restrict__ out_b,
                           const float* __restrict__ ipb, float* __restrict__ b2c)
{
  __shared__ float pb[256];
  const int m = blockIdx.x, o = threadIdx.x;
  pb[o] = ipb[(size_t)m*768 + 512 + o];
  __syncthreads();
  const float* wr = out_w + ((size_t)m*256 + o)*256;
  float acc = out_b[(size_t)m*256 + o];
  for (int f = 0; f < 256; f += 4) {
    f4 w = *(const f4*)&wr[f];
    acc += w.x*pb[f] + w.y*pb[f+1] + w.z*pb[f+2] + w.w*pb[f+3];
  }
  b2c[(size_t)m*256 + o] = acc;
}

// ---------------------------------------------------------------------------
// f32 row-major [C][K] -> fragment-linear bf16
__device__ __forceinline__ void cvt_seg(const float* __restrict__ src, u16* __restrict__ dst,
                                        int Creal, int lognks, int g)
{
  const int l = g & 63;
  const int cks = g >> 6;
  const int ks = cks & ((1 << lognks) - 1);
  const int ct = cks >> lognks;
  const int c = ct*32 + (l & 31);
  const int K = 16 << lognks;
  const int k = ks*16 + ((l >> 5) * 8);
  s16x8 r;
  if (c < Creal) {
    const float* s = src + (size_t)c * K + k;
    f4 v0 = *(const f4*)s;
    f4 v1 = *(const f4*)(s + 4);
    r[0]=(short)f2bf(v0.x); r[1]=(short)f2bf(v0.y); r[2]=(short)f2bf(v0.z); r[3]=(short)f2bf(v0.w);
    r[4]=(short)f2bf(v1.x); r[5]=(short)f2bf(v1.y); r[6]=(short)f2bf(v1.z); r[7]=(short)f2bf(v1.w);
  } else {
#pragma unroll
    for (int j = 0; j < 8; ++j) r[j] = 0;
  }
  *(s16x8*)(dst + (size_t)g * 8) = r;
}

__global__ __launch_bounds__(256)
void wcvt_all(const float* __restrict__ whh0, const float* __restrict__ wih1,
              const float* __restrict__ whh1, const float* __restrict__ W2c,
              const float* __restrict__ ffn1, const float* __restrict__ ffn2,
              const float* __restrict__ dec1, const float* __restrict__ dec2,
              const float* __restrict__ sc1,  u16* __restrict__ dst)
{
  int g = blockIdx.x * 256 + threadIdx.x;
  if      (g <  32768) cvt_seg(whh0, dst + 0,       1024, 4, g);
  else if (g <  65536) cvt_seg(wih1, dst + 262144,  1024, 4, g - 32768);
  else if (g <  98304) cvt_seg(whh1, dst + 524288,  1024, 4, g - 65536);
  else if (g < 262144) cvt_seg(W2c,  dst + 786432,  5120, 4, g - 98304);
  else if (g < 294912) cvt_seg(ffn1, dst + 2097152, 1024, 4, g - 262144);
  else if (g < 327680) cvt_seg(ffn2, dst + 2359296,  256, 6, g - 294912);
  else if (g < 344064) cvt_seg(dec1, dst + 2621440,  512, 4, g - 327680);
  else if (g < 346112) cvt_seg(dec2, dst + 2752512,   24, 5, g - 344064);
  else if (g < 350208) cvt_seg(sc1,  dst + 2768896,  128, 4, g - 346112);
}

// ---------------------------------------------------------------------------
// Fused LSTM: 256 blocks x 32 rows, 512 thr (8 waves). Wave w owns e-block
// [w*32, w*32+32) with all 4 gates (ct = g*8 + w). h bf16 in LDS, c fp32 regs.
__global__ __launch_bounds__(512, 2)
void lstm_fused(const u16* __restrict__ whh0f, const u16* __restrict__ wih1f,
                const u16* __restrict__ whh1f, const float* __restrict__ w_ih0,
                const float* __restrict__ b_ih0, const float* __restrict__ b_hh0,
                const float* __restrict__ b_ih1, const float* __restrict__ b_hh1,
                const float* __restrict__ obs, u16* __restrict__ emb)
{
  __shared__ u16 h0s[32 * LSTR];
  __shared__ u16 h1s[32 * LSTR];
  __shared__ float obs_s[512];
  const int tid = threadIdx.x;
  const int lane = tid & 63, w = tid >> 6;
  const int col = lane & 31, hi = lane >> 5;
  const int r0 = blockIdx.x * 32;
  if (tid < 512) obs_s[tid] = obs[(size_t)r0 * 16 + tid];

  float bs0[4], bs1[4], xw0[4], xw1[4];
#pragma unroll
  for (int g = 0; g < 4; ++g) {
    const int cg = g*256 + w*32 + col;
    bs0[g] = b_ih0[cg] + b_hh0[cg];
    bs1[g] = b_ih1[cg] + b_hh1[cg];
    xw0[g] = w_ih0[2*cg];
    xw1[g] = w_ih0[2*cg + 1];
  }
  float c0v[16], c1v[16];
#pragma unroll
  for (int r = 0; r < 16; ++r) { c0v[r] = 0.f; c1v[r] = 0.f; }

  f32x16 za;
#pragma unroll
  for (int i = 0; i < 16; ++i) za[i] = 0.f;

  __syncthreads();

  for (int t = 0; t < 8; ++t) {
    f32x16 accA[4], accB[4];
#pragma unroll
    for (int g = 0; g < 4; ++g) { accA[g] = za; accB[g] = za; }
    if (t > 0) {
      // phase1: both recurrences concurrently (8 indep chains, 8 loads/ks)
#pragma unroll 2
      for (int ks = 0; ks < 16; ++ks) {
        s16x8 a0 = *(const s16x8*)(h0s + col*LSTR + ks*16 + hi*8);
        s16x8 a1 = *(const s16x8*)(h1s + col*LSTR + ks*16 + hi*8);
#pragma unroll
        for (int g = 0; g < 4; ++g) {
          const size_t fo = ((size_t)((g*8 + w)*16 + ks)*64 + lane)*8;
          s16x8 bA = *(const s16x8*)(whh0f + fo);
          accA[g] = __builtin_amdgcn_mfma_f32_32x32x16_bf16(a0, bA, accA[g], 0, 0, 0);
          s16x8 bB = *(const s16x8*)(whh1f + fo);
          accB[g] = __builtin_amdgcn_mfma_f32_32x32x16_bf16(a1, bB, accB[g], 0, 0, 0);
        }
      }
    }
    __syncthreads();          // all reads of h0s/h1s done
    // epilogue layer0 -> h0s
#pragma unroll
    for (int r = 0; r < 16; ++r) {
      const int row = (r&3) + 8*(r>>2) + 4*hi;
      const float x0 = obs_s[row*16 + 2*t], x1 = obs_s[row*16 + 2*t + 1];
      const float gi = accA[0][r] + bs0[0] + x0*xw0[0] + x1*xw1[0];
      const float gf = accA[1][r] + bs0[1] + x0*xw0[1] + x1*xw1[1];
      const float gg = accA[2][r] + bs0[2] + x0*xw0[2] + x1*xw1[2];
      const float go = accA[3][r] + bs0[3] + x0*xw0[3] + x1*xw1[3];
      const float cn = sigm(gf)*c0v[r] + sigm(gi)*tanhfast(gg);
      c0v[r] = cn;
      h0s[row*LSTR + w*32 + col] = f2bf(sigm(go)*tanhfast(cn));
    }
    __syncthreads();          // h0s new visible
    // phase2: accB += h0_new @ wih1
#pragma unroll 2
    for (int ks = 0; ks < 16; ++ks) {
      s16x8 a = *(const s16x8*)(h0s + col*LSTR + ks*16 + hi*8);
#pragma unroll
      for (int g = 0; g < 4; ++g) {
        s16x8 b = *(const s16x8*)(wih1f + ((size_t)((g*8 + w)*16 + ks)*64 + lane)*8);
        accB[g] = __builtin_amdgcn_mfma_f32_32x32x16_bf16(a, b, accB[g], 0, 0, 0);
      }
    }
    // epilogue layer1 -> h1s (h1s reads all finished at bar after phase1)
#pragma unroll
    for (int r = 0; r < 16; ++r) {
      const int row = (r&3) + 8*(r>>2) + 4*hi;
      const float gi = accB[0][r] + bs1[0];
      const float gf = accB[1][r] + bs1[1];
      const float gg = accB[2][r] + bs1[2];
      const float go = accB[3][r] + bs1[3];
      const float cn = sigm(gf)*c1v[r] + sigm(gi)*tanhfast(gg);
      c1v[r] = cn;
      h1s[row*LSTR + w*32 + col] = f2bf(sigm(go)*tanhfast(cn));
    }
    __syncthreads();          // h1s new visible for next t
  }
  // emb = h1[7]
#pragma unroll
  for (int kk = 0; kk < 2; ++kk) {
    const int gi2 = tid + kk*512;
    const int row = gi2 >> 5, grp = gi2 & 31;
    *(s16x8*)(emb + (size_t)(r0 + row)*256 + grp*8) = *(const s16x8*)(h1s + row*LSTR + grp*8);
  }
}

// ---------------------------------------------------------------------------
// mode_stack: 512 thr (8 waves), 128 rows x one mode. grid (64, 20).
// Wave w = col-tile w (32 cols), all 4 row-tiles: 4 MFMA per B-fragment load.
__device__ __forceinline__ void gemm128(const u16* As, const u16* __restrict__ Bf,
                                        f32x16 acc[4], int w, int lane)
{
  const int col = lane & 31, hi = lane >> 5;
#pragma unroll 4
  for (int ks = 0; ks < 16; ++ks) {
    s16x8 b = *(const s16x8*)(Bf + ((size_t)(w*16 + ks)*64 + lane)*8);
#pragma unroll
    for (int i = 0; i < 4; ++i) {
      s16x8 a = *(const s16x8*)(As + (i*32 + col)*LSTR + ks*16 + hi*8);
      acc[i] = __builtin_amdgcn_mfma_f32_32x32x16_bf16(a, b, acc[i], 0, 0, 0);
    }
  }
}

__device__ __forceinline__ void gemm_ffn2_128(const u16* As, const u16* __restrict__ Bf,
                                              f32x16 acc[4], int c4, int w, int lane)
{
  const int col = lane & 31, hi = lane >> 5;
#pragma unroll 4
  for (int ks = 0; ks < 16; ++ks) {
    s16x8 b = *(const s16x8*)(Bf + ((size_t)(w*64 + c4*16 + ks)*64 + lane)*8);
#pragma unroll
    for (int i = 0; i < 4; ++i) {
      s16x8 a = *(const s16x8*)(As + (i*32 + col)*LSTR + ks*16 + hi*8);
      acc[i] = __builtin_amdgcn_mfma_f32_32x32x16_bf16(a, b, acc[i], 0, 0, 0);
    }
  }
}

template<int ACT>
__device__ __forceinline__ void epi_store128(f32x16 acc[4], const float* __restrict__ bias,
                                             u16* Ys, int w, int lane)
{
  const int col = lane & 31, hi = lane >> 5, cg = w*32 + col;
  const float bv = bias[cg];
#pragma unroll
  for (int i = 0; i < 4; ++i)
#pragma unroll
    for (int r = 0; r < 16; ++r) {
      float v = acc[i][r] + bv;
      if (ACT == 1) v = fmaxf(v, 0.f);
      else if (ACT == 2) v = eluf(v);
      const int row = i*32 + (r&3) + 8*(r>>2) + 4*hi;
      Ys[row*LSTR + cg] = f2bf(v);
    }
}

__device__ __forceinline__ void lnpass128(const u16* In, u16* Out,
    const float* __restrict__ g, const float* __restrict__ b, int tid)
{
  const int lane = tid & 63, w = tid >> 6;
  f4 gv = *(const f4*)&g[lane*4];
  f4 bv = *(const f4*)&b[lane*4];
#pragma unroll
  for (int i = 0; i < 16; ++i) {
    const int row = w*16 + i;
    ushort4 uv = *(const ushort4*)(In + row*LSTR + lane*4);
    float v0 = bf2f(uv.x), v1 = bf2f(uv.y), v2 = bf2f(uv.z), v3 = bf2f(uv.w);
    float s  = v0 + v1 + v2 + v3;
    float ss = v0*v0 + v1*v1 + v2*v2 + v3*v3;
#pragma unroll
    for (int d = 1; d < 64; d <<= 1) { s += __shfl_xor(s, d); ss += __shfl_xor(ss, d); }
    const float mean = s * (1.f/256.f);
    const float rs = rsqrtf(ss * (1.f/256.f) - mean*mean + 1e-5f);
    ushort4 o;
    o.x = f2bf((v0 - mean)*rs*gv.x + bv.x);
    o.y = f2bf((v1 - mean)*rs*gv.y + bv.y);
    o.z = f2bf((v2 - mean)*rs*gv.z + bv.z);
    o.w = f2bf((v3 - mean)*rs*gv.w + bv.w);
    *(ushort4*)(Out + row*LSTR + lane*4) = o;
  }
}

__global__ __launch_bounds__(512, 2)
void mode_stack(const u16* __restrict__ emb, const u16* __restrict__ W2cf,
  const float* __restrict__ b2c,
  const float* __restrict__ ln1_g, const float* __restrict__ ln1_b,
  const u16* __restrict__ ffn1f, const float* __restrict__ ffn_b1,
  const u16* __restrict__ ffn2f, const float* __restrict__ ffn_b2,
  const float* __restrict__ ln2_g, const float* __restrict__ ln2_b,
  const u16* __restrict__ dec1f, const float* __restrict__ dec_b1,
  const u16* __restrict__ dec2f, const float* __restrict__ dec_b2,
  const u16* __restrict__ sc1f,  const float* __restrict__ sc_b1,
  const float* __restrict__ sc_w2, const float* __restrict__ sc_b2,
  const float* __restrict__ obs, float* __restrict__ pred, float* __restrict__ score)
{
  __shared__ u16 Xs[128 * LSTR];
  __shared__ u16 Ys[128 * LSTR];
  __shared__ float obs_ls[256];
  const int tid = threadIdx.x;
  const int lane = tid & 63, w = tid >> 6;
  const int col = lane & 31, hi = lane >> 5;
  const int r0 = blockIdx.x * 128;
  const int m  = blockIdx.y;

  f32x16 za;
#pragma unroll
  for (int i = 0; i < 16; ++i) za[i] = 0.f;

#pragma unroll
  for (int kk = 0; kk < 8; ++kk) {
    const int gi2 = tid + kk*512;
    const int row = gi2 >> 5, grp = gi2 & 31;
    *(s16x8*)(Xs + row*LSTR + grp*8) = *(const s16x8*)(emb + (size_t)(r0 + row)*256 + grp*8);
  }
  if (tid < 256) obs_ls[tid] = obs[(size_t)(r0 + (tid >> 1))*16 + 14 + (tid & 1)];
  __syncthreads();

  { // attn-out (fused v-proj + out-proj)
    f32x16 acc[4];
#pragma unroll
    for (int i = 0; i < 4; ++i) acc[i] = za;
    gemm128(Xs, W2cf + (size_t)m*65536, acc, w, lane);
    epi_store128<0>(acc, b2c + m*256, Ys, w, lane);
  }
  __syncthreads();
  lnpass128(Ys, Xs, ln1_g, ln1_b, tid);   // Xs = h1
  __syncthreads();

  f32x16 h2[4];
#pragma unroll
  for (int i = 0; i < 4; ++i) h2[i] = za;
  for (int c4 = 0; c4 < 4; ++c4) {
    f32x16 tacc[4];
#pragma unroll
    for (int i = 0; i < 4; ++i) tacc[i] = za;
    gemm128(Xs, ffn1f + (size_t)c4*65536, tacc, w, lane);
    epi_store128<1>(tacc, ffn_b1 + c4*256, Ys, w, lane);
    __syncthreads();
    gemm_ffn2_128(Ys, ffn2f, h2, c4, w, lane);
    __syncthreads();
  }
  epi_store128<0>(h2, ffn_b2, Ys, w, lane);
  __syncthreads();
  lnpass128(Ys, Xs, ln2_g, ln2_b, tid);   // Xs = mm_emb
  __syncthreads();

  f32x16 dv[4];
#pragma unroll
  for (int i = 0; i < 4; ++i) dv[i] = za;
  for (int c2 = 0; c2 < 2; ++c2) {
    f32x16 tacc[4];
#pragma unroll
    for (int i = 0; i < 4; ++i) tacc[i] = za;
    gemm128(Xs, dec1f + (size_t)c2*65536, tacc, w, lane);
    epi_store128<2>(tacc, dec_b1 + c2*256, Ys, w, lane);
    __syncthreads();
    if (w == 0) {   // dec2: 1 wave, 4 row-tiles, 32 cols (24 real)
#pragma unroll 4
      for (int ks = 0; ks < 16; ++ks) {
        s16x8 b = *(const s16x8*)(dec2f + ((size_t)(c2*16 + ks)*64 + lane)*8);
#pragma unroll
        for (int i = 0; i < 4; ++i) {
          s16x8 a = *(const s16x8*)(Ys + (i*32 + col)*LSTR + ks*16 + hi*8);
          dv[i] = __builtin_amdgcn_mfma_f32_32x32x16_bf16(a, b, dv[i], 0, 0, 0);
        }
      }
    }
    __syncthreads();
  }
  // predictions epilogue (deltas + last_pos) — frees dv before score head
  if (w == 0 && col < 24) {
    const float db = dec_b2[col];
#pragma unroll
    for (int i = 0; i < 4; ++i)
#pragma unroll
      for (int r = 0; r < 16; ++r) {
        const int row = i*32 + (r&3) + 8*(r>>2) + 4*hi;
        const float lp = obs_ls[row*2 + (col & 1)];
        pred[((size_t)(r0 + row)*20 + m)*24 + col] = dv[i][r] + db + lp;
      }
  }

  if (w < 4) { // score head layer 1: 128 cols, 4 col-tiles over waves 0..3
    f32x16 sacc[4];
#pragma unroll
    for (int i = 0; i < 4; ++i) sacc[i] = za;
    gemm128(Xs, sc1f, sacc, w, lane);
    epi_store128<2>(sacc, sc_b1, Ys, w, lane);
  }
  __syncthreads();
  { // score head layer 2: dot(128) per row
    const float scb2 = sc_b2[0];
    const float2 w2v = *(const float2*)&sc_w2[lane*2];
#pragma unroll
    for (int i = 0; i < 16; ++i) {
      const int row = w*16 + i;
      u32 pv = *(const u32*)(Ys + row*LSTR + lane*2);
      float part = bf2f((u16)(pv & 0xFFFF))*w2v.x + bf2f((u16)(pv >> 16))*w2v.y;
#pragma unroll
      for (int d = 1; d < 64; d <<= 1) part += __shfl_xor(part, d);
      if (lane == 0) score[(size_t)(r0 + row)*20 + m] = part + scb2;
    }
  }
}

// ---------------------------------------------------------------------------
extern "C" void kernel_launch(void* const* d_in, const int* in_sizes, int n_in,
                              void* d_out, int out_size, void* d_ws, size_t ws_size,
                              hipStream_t stream)
{
  (void)in_sizes; (void)n_in; (void)out_size; (void)ws_size;
  const float* obs    = (const float*)d_in[0];
  const float* w_ih0  = (const float*)d_in[1];
  const float* w_hh0  = (const float*)d_in[2];
  const float* b_ih0  = (const float*)d_in[3];
  const float* b_hh0  = (const float*)d_in[4];
  const float* w_ih1  = (const float*)d_in[5];
  const float* w_hh1  = (const float*)d_in[6];
  const float* b_ih1  = (const float*)d_in[7];
  const float* b_hh1  = (const float*)d_in[8];
  const float* ipw    = (const float*)d_in[9];
  const float* ipb    = (const float*)d_in[10];
  const float* out_w  = (const float*)d_in[11];
  const float* out_b  = (const float*)d_in[12];
  const float* ln1_g  = (const float*)d_in[13];
  const float* ln1_b  = (const float*)d_in[14];
  const float* ffn_w1 = (const float*)d_in[15];
  const float* ffn_b1 = (const float*)d_in[16];
  const float* ffn_w2 = (const float*)d_in[17];
  const float* ffn_b2 = (const float*)d_in[18];
  const float* ln2_g  = (const float*)d_in[19];
  const float* ln2_b  = (const float*)d_in[20];
  const float* dec_w1 = (const float*)d_in[21];
  const float* dec_b1 = (const float*)d_in[22];
  const float* dec_w2 = (const float*)d_in[23];
  const float* dec_b2 = (const float*)d_in[24];
  const float* sc_w1  = (const float*)d_in[25];
  const float* sc_b1  = (const float*)d_in[26];
  const float* sc_w2  = (const float*)d_in[27];
  const float* sc_b2  = (const float*)d_in[28];

  float* outp   = (float*)d_out;
  float* pred   = outp;
  float* scoreo = outp + (size_t)8192*20*24;

  // workspace layout
  float* wsf   = (float*)d_ws;
  float* W2c   = wsf;                         // 1310720 f32
  float* b2cp  = wsf + 1310720;               // 5120 f32
  u16*   wsh   = (u16*)(wsf + 1315840);       // 16B-aligned
  u16* whh0f = wsh + 0;
  u16* wih1f = wsh + 262144;
  u16* whh1f = wsh + 524288;
  u16* W2cf  = wsh + 786432;
  u16* ffn1f = wsh + 2097152;
  u16* ffn2f = wsh + 2359296;
  u16* dec1f = wsh + 2621440;
  u16* dec2f = wsh + 2752512;
  u16* sc1f  = wsh + 2768896;
  u16* emb   = wsh + 2801664;                 // 8192*256 bf16

  w2c_kernel<<<dim3(16, 20), 256, 0, stream>>>(out_w, ipw, W2c);
  b2c_kernel<<<20, 256, 0, stream>>>(out_w, out_b, ipb, b2cp);
  wcvt_all<<<1368, 256, 0, stream>>>(w_hh0, w_ih1, w_hh1, W2c, ffn_w1, ffn_w2,
                                     dec_w1, dec_w2, sc_w1, wsh);
  lstm_fused<<<256, 512, 0, stream>>>(whh0f, wih1f, whh1f, w_ih0, b_ih0, b_hh0,
                                      b_ih1, b_hh1, obs, emb);
  mode_stack<<<dim3(64, 20), 512, 0, stream>>>(emb, W2cf, b2cp,
      ln1_g, ln1_b, ffn1f, ffn_b1, ffn2f, ffn_b2, ln2_g, ln2_b,
      dec1f, dec_b1, dec2f, dec_b2, sc1f, sc_b1, sc_w2, sc_b2,
      obs, pred, scoreo);
}

// Round 5
// 811.339 us; speedup vs baseline: 8.9560x; 1.0451x over previous
//
#include <hip/hip_runtime.h>
#include <math.h>

// PredictorNoEgo: B=8192 T=8 E=256 M=20 FS=12
// Algebra: softmax over size-1 axis == 1 => ctx == v (q,k dead);
//          attn_out = emb @ (out_w[m] @ Wv[m])^T + (out_w[m]@bv[m] + out_b[m])
// R5: mode_stack -> 1024 thr / 16 waves / 128 rows: keeps the 128-row tile's
// low B-traffic AND 4 waves/SIMD TLP (R4 had only 2). Wave w: col-tile w&7,
// row-half w>>3. LSTM: phase2 unroll 4.

typedef float4 f4;
typedef unsigned int u32;
typedef unsigned short u16;
typedef __attribute__((ext_vector_type(16))) float f32x16;
typedef __attribute__((ext_vector_type(8)))  short s16x8;

__device__ __forceinline__ float sigm(float x){ return 1.0f/(1.0f + __expf(-x)); }
__device__ __forceinline__ float tanhfast(float x){ return 2.0f*sigm(2.0f*x) - 1.0f; }
__device__ __forceinline__ float eluf(float x){ return x > 0.f ? x : expm1f(x); }
__device__ __forceinline__ u16 f2bf(float x){
  u32 u = __float_as_uint(x);
  return (u16)((u + 0x7FFFu + ((u>>16)&1u)) >> 16);
}
__device__ __forceinline__ float bf2f(u16 h){ return __uint_as_float(((u32)h)<<16); }

// MFMA 32x32x16 bf16: A lane l: A[row=l&31][k=(l>>5)*8+j]; B lane l: B[k][col=l&31]
// C/D reg r: row=(r&3)+8*(r>>2)+4*(l>>5), col=l&31
// Fragment-linear W' (row-major W[C][K]): elem ((ct*(K/16)+ks)*64+l)*8+j
//   = W[ct*32+(l&31)][ks*16+(l>>5)*8+j]

#define LSTR 264  // LDS row stride in u16 (528B): 16B-aligned, bank-balanced

// ---------------------------------------------------------------------------
// W2c[m] = out_w[m] (256x256) @ in_proj_w[m,512:768,:] (256x256)   (fp32)
__global__ __launch_bounds__(256, 4)
void w2c_kernel(const float* __restrict__ out_w, const float* __restrict__ ipw,
                float* __restrict__ W2c)
{
  __shared__ float As[16][68];
  __shared__ float Bs2[16][68];
  const int tid = threadIdx.x;
  const int m = blockIdx.y;
  const int o0 = (blockIdx.x >> 2) * 64, e0 = (blockIdx.x & 3) * 64;
  const int trow = tid >> 4, tcol = tid & 15;
  const float* Ap = out_w + (size_t)m * 65536;
  const float* Bp = ipw + ((size_t)m * 768 + 512) * 256;
  float acc[16];
#pragma unroll
  for (int z = 0; z < 16; ++z) acc[z] = 0.f;
  for (int kb = 0; kb < 256; kb += 16) {
    { int row = tid >> 2, ko = (tid & 3) * 4;
      f4 v = *(const f4*)(Ap + (size_t)(o0+row)*256 + kb + ko);
      As[ko+0][row]=v.x; As[ko+1][row]=v.y; As[ko+2][row]=v.z; As[ko+3][row]=v.w; }
    { int k = tid >> 4, eo = (tid & 15) * 4;
      *(f4*)&Bs2[k][eo] = *(const f4*)(Bp + (size_t)(kb+k)*256 + e0 + eo); }
    __syncthreads();
#pragma unroll
    for (int k = 0; k < 16; ++k) {
      f4 a4 = *(const f4*)&As[k][trow*4];
      f4 b4 = *(const f4*)&Bs2[k][tcol*4];
      acc[0]+=a4.x*b4.x; acc[1]+=a4.x*b4.y; acc[2]+=a4.x*b4.z; acc[3]+=a4.x*b4.w;
      acc[4]+=a4.y*b4.x; acc[5]+=a4.y*b4.y; acc[6]+=a4.y*b4.z; acc[7]+=a4.y*b4.w;
      acc[8]+=a4.z*b4.x; acc[9]+=a4.z*b4.y; acc[10]+=a4.z*b4.z; acc[11]+=a4.z*b4.w;
      acc[12]+=a4.w*b4.x; acc[13]+=a4.w*b4.y; acc[14]+=a4.w*b4.z; acc[15]+=a4.w*b4.w;
    }
    __syncthreads();
  }
#pragma unroll
  for (int i = 0; i < 4; ++i)
    *(f4*)&W2c[((size_t)m*256 + o0 + trow*4 + i)*256 + e0 + tcol*4] =
        make_float4(acc[i*4+0], acc[i*4+1], acc[i*4+2], acc[i*4+3]);
}

__global__ void b2c_kernel(const float* __restrict__ out_w, const float* __restrict__ out_b,
                           const float* __restrict__ ipb, float* __restrict__ b2c)
{
  __shared__ float pb[256];
  const int m = blockIdx.x, o = threadIdx.x;
  pb[o] = ipb[(size_t)m*768 + 512 + o];
  __syncthreads();
  const float* wr = out_w + ((size_t)m*256 + o)*256;
  float acc = out_b[(size_t)m*256 + o];
  for (int f = 0; f < 256; f += 4) {
    f4 w = *(const f4*)&wr[f];
    acc += w.x*pb[f] + w.y*pb[f+1] + w.z*pb[f+2] + w.w*pb[f+3];
  }
  b2c[(size_t)m*256 + o] = acc;
}

// ---------------------------------------------------------------------------
// f32 row-major [C][K] -> fragment-linear bf16
__device__ __forceinline__ void cvt_seg(const float* __restrict__ src, u16* __restrict__ dst,
                                        int Creal, int lognks, int g)
{
  const int l = g & 63;
  const int cks = g >> 6;
  const int ks = cks & ((1 << lognks) - 1);
  const int ct = cks >> lognks;
  const int c = ct*32 + (l & 31);
  const int K = 16 << lognks;
  const int k = ks*16 + ((l >> 5) * 8);
  s16x8 r;
  if (c < Creal) {
    const float* s = src + (size_t)c * K + k;
    f4 v0 = *(const f4*)s;
    f4 v1 = *(const f4*)(s + 4);
    r[0]=(short)f2bf(v0.x); r[1]=(short)f2bf(v0.y); r[2]=(short)f2bf(v0.z); r[3]=(short)f2bf(v0.w);
    r[4]=(short)f2bf(v1.x); r[5]=(short)f2bf(v1.y); r[6]=(short)f2bf(v1.z); r[7]=(short)f2bf(v1.w);
  } else {
#pragma unroll
    for (int j = 0; j < 8; ++j) r[j] = 0;
  }
  *(s16x8*)(dst + (size_t)g * 8) = r;
}

__global__ __launch_bounds__(256)
void wcvt_all(const float* __restrict__ whh0, const float* __restrict__ wih1,
              const float* __restrict__ whh1, const float* __restrict__ W2c,
              const float* __restrict__ ffn1, const float* __restrict__ ffn2,
              const float* __restrict__ dec1, const float* __restrict__ dec2,
              const float* __restrict__ sc1,  u16* __restrict__ dst)
{
  int g = blockIdx.x * 256 + threadIdx.x;
  if      (g <  32768) cvt_seg(whh0, dst + 0,       1024, 4, g);
  else if (g <  65536) cvt_seg(wih1, dst + 262144,  1024, 4, g - 32768);
  else if (g <  98304) cvt_seg(whh1, dst + 524288,  1024, 4, g - 65536);
  else if (g < 262144) cvt_seg(W2c,  dst + 786432,  5120, 4, g - 98304);
  else if (g < 294912) cvt_seg(ffn1, dst + 2097152, 1024, 4, g - 262144);
  else if (g < 327680) cvt_seg(ffn2, dst + 2359296,  256, 6, g - 294912);
  else if (g < 344064) cvt_seg(dec1, dst + 2621440,  512, 4, g - 327680);
  else if (g < 346112) cvt_seg(dec2, dst + 2752512,   24, 5, g - 344064);
  else if (g < 350208) cvt_seg(sc1,  dst + 2768896,  128, 4, g - 346112);
}

// ---------------------------------------------------------------------------
// Fused LSTM: 256 blocks x 32 rows, 512 thr (8 waves). Wave w owns e-block
// [w*32, w*32+32) with all 4 gates (ct = g*8 + w). h bf16 in LDS, c fp32 regs.
__global__ __launch_bounds__(512, 2)
void lstm_fused(const u16* __restrict__ whh0f, const u16* __restrict__ wih1f,
                const u16* __restrict__ whh1f, const float* __restrict__ w_ih0,
                const float* __restrict__ b_ih0, const float* __restrict__ b_hh0,
                const float* __restrict__ b_ih1, const float* __restrict__ b_hh1,
                const float* __restrict__ obs, u16* __restrict__ emb)
{
  __shared__ u16 h0s[32 * LSTR];
  __shared__ u16 h1s[32 * LSTR];
  __shared__ float obs_s[512];
  const int tid = threadIdx.x;
  const int lane = tid & 63, w = tid >> 6;
  const int col = lane & 31, hi = lane >> 5;
  const int r0 = blockIdx.x * 32;
  if (tid < 512) obs_s[tid] = obs[(size_t)r0 * 16 + tid];

  float bs0[4], bs1[4], xw0[4], xw1[4];
#pragma unroll
  for (int g = 0; g < 4; ++g) {
    const int cg = g*256 + w*32 + col;
    bs0[g] = b_ih0[cg] + b_hh0[cg];
    bs1[g] = b_ih1[cg] + b_hh1[cg];
    xw0[g] = w_ih0[2*cg];
    xw1[g] = w_ih0[2*cg + 1];
  }
  float c0v[16], c1v[16];
#pragma unroll
  for (int r = 0; r < 16; ++r) { c0v[r] = 0.f; c1v[r] = 0.f; }

  f32x16 za;
#pragma unroll
  for (int i = 0; i < 16; ++i) za[i] = 0.f;

  __syncthreads();

  for (int t = 0; t < 8; ++t) {
    f32x16 accA[4], accB[4];
#pragma unroll
    for (int g = 0; g < 4; ++g) { accA[g] = za; accB[g] = za; }
    if (t > 0) {
      // phase1: both recurrences concurrently (8 indep chains, 8 loads/ks)
#pragma unroll 2
      for (int ks = 0; ks < 16; ++ks) {
        s16x8 a0 = *(const s16x8*)(h0s + col*LSTR + ks*16 + hi*8);
        s16x8 a1 = *(const s16x8*)(h1s + col*LSTR + ks*16 + hi*8);
#pragma unroll
        for (int g = 0; g < 4; ++g) {
          const size_t fo = ((size_t)((g*8 + w)*16 + ks)*64 + lane)*8;
          s16x8 bA = *(const s16x8*)(whh0f + fo);
          accA[g] = __builtin_amdgcn_mfma_f32_32x32x16_bf16(a0, bA, accA[g], 0, 0, 0);
          s16x8 bB = *(const s16x8*)(whh1f + fo);
          accB[g] = __builtin_amdgcn_mfma_f32_32x32x16_bf16(a1, bB, accB[g], 0, 0, 0);
        }
      }
    }
    __syncthreads();          // all reads of h0s/h1s done
    // epilogue layer0 -> h0s
#pragma unroll
    for (int r = 0; r < 16; ++r) {
      const int row = (r&3) + 8*(r>>2) + 4*hi;
      const float x0 = obs_s[row*16 + 2*t], x1 = obs_s[row*16 + 2*t + 1];
      const float gi = accA[0][r] + bs0[0] + x0*xw0[0] + x1*xw1[0];
      const float gf = accA[1][r] + bs0[1] + x0*xw0[1] + x1*xw1[1];
      const float gg = accA[2][r] + bs0[2] + x0*xw0[2] + x1*xw1[2];
      const float go = accA[3][r] + bs0[3] + x0*xw0[3] + x1*xw1[3];
      const float cn = sigm(gf)*c0v[r] + sigm(gi)*tanhfast(gg);
      c0v[r] = cn;
      h0s[row*LSTR + w*32 + col] = f2bf(sigm(go)*tanhfast(cn));
    }
    __syncthreads();          // h0s new visible
    // phase2: accB += h0_new @ wih1
#pragma unroll 4
    for (int ks = 0; ks < 16; ++ks) {
      s16x8 a = *(const s16x8*)(h0s + col*LSTR + ks*16 + hi*8);
#pragma unroll
      for (int g = 0; g < 4; ++g) {
        s16x8 b = *(const s16x8*)(wih1f + ((size_t)((g*8 + w)*16 + ks)*64 + lane)*8);
        accB[g] = __builtin_amdgcn_mfma_f32_32x32x16_bf16(a, b, accB[g], 0, 0, 0);
      }
    }
    // epilogue layer1 -> h1s (h1s reads all finished at bar after phase1)
#pragma unroll
    for (int r = 0; r < 16; ++r) {
      const int row = (r&3) + 8*(r>>2) + 4*hi;
      const float gi = accB[0][r] + bs1[0];
      const float gf = accB[1][r] + bs1[1];
      const float gg = accB[2][r] + bs1[2];
      const float go = accB[3][r] + bs1[3];
      const float cn = sigm(gf)*c1v[r] + sigm(gi)*tanhfast(gg);
      c1v[r] = cn;
      h1s[row*LSTR + w*32 + col] = f2bf(sigm(go)*tanhfast(cn));
    }
    __syncthreads();          // h1s new visible for next t
  }
  // emb = h1[7]
#pragma unroll
  for (int kk = 0; kk < 2; ++kk) {
    const int gi2 = tid + kk*512;
    const int row = gi2 >> 5, grp = gi2 & 31;
    *(s16x8*)(emb + (size_t)(r0 + row)*256 + grp*8) = *(const s16x8*)(h1s + row*LSTR + grp*8);
  }
}

// ---------------------------------------------------------------------------
// mode_stack: 1024 thr (16 waves), 128 rows x one mode. grid (64, 20).
// Wave w: col-tile ct=w&7, row-half rh=w>>3 (row-tiles 2rh, 2rh+1).
// 2 MFMA per B-load; (w, w+8) share B-frags via L1.
__device__ __forceinline__ void gemm128(const u16* As, const u16* __restrict__ Bf,
                                        f32x16 acc[2], int ct, int rh, int lane)
{
  const int col = lane & 31, hi = lane >> 5;
#pragma unroll 4
  for (int ks = 0; ks < 16; ++ks) {
    s16x8 b = *(const s16x8*)(Bf + ((size_t)(ct*16 + ks)*64 + lane)*8);
#pragma unroll
    for (int i = 0; i < 2; ++i) {
      s16x8 a = *(const s16x8*)(As + ((rh*2 + i)*32 + col)*LSTR + ks*16 + hi*8);
      acc[i] = __builtin_amdgcn_mfma_f32_32x32x16_bf16(a, b, acc[i], 0, 0, 0);
    }
  }
}

__device__ __forceinline__ void gemm_ffn2_128(const u16* As, const u16* __restrict__ Bf,
                                              f32x16 acc[2], int c4, int ct, int rh, int lane)
{
  const int col = lane & 31, hi = lane >> 5;
#pragma unroll 4
  for (int ks = 0; ks < 16; ++ks) {
    s16x8 b = *(const s16x8*)(Bf + ((size_t)(ct*64 + c4*16 + ks)*64 + lane)*8);
#pragma unroll
    for (int i = 0; i < 2; ++i) {
      s16x8 a = *(const s16x8*)(As + ((rh*2 + i)*32 + col)*LSTR + ks*16 + hi*8);
      acc[i] = __builtin_amdgcn_mfma_f32_32x32x16_bf16(a, b, acc[i], 0, 0, 0);
    }
  }
}

template<int ACT>
__device__ __forceinline__ void epi_store128(f32x16 acc[2], const float* __restrict__ bias,
                                             u16* Ys, int ct, int rh, int lane)
{
  const int col = lane & 31, hi = lane >> 5, cg = ct*32 + col;
  const float bv = bias[cg];
#pragma unroll
  for (int i = 0; i < 2; ++i)
#pragma unroll
    for (int r = 0; r < 16; ++r) {
      float v = acc[i][r] + bv;
      if (ACT == 1) v = fmaxf(v, 0.f);
      else if (ACT == 2) v = eluf(v);
      const int row = (rh*2 + i)*32 + (r&3) + 8*(r>>2) + 4*hi;
      Ys[row*LSTR + cg] = f2bf(v);
    }
}

__device__ __forceinline__ void lnpass128(const u16* In, u16* Out,
    const float* __restrict__ g, const float* __restrict__ b, int tid)
{
  const int lane = tid & 63, w = tid >> 6;   // 16 waves x 8 rows
  f4 gv = *(const f4*)&g[lane*4];
  f4 bv = *(const f4*)&b[lane*4];
#pragma unroll
  for (int i = 0; i < 8; ++i) {
    const int row = w*8 + i;
    ushort4 uv = *(const ushort4*)(In + row*LSTR + lane*4);
    float v0 = bf2f(uv.x), v1 = bf2f(uv.y), v2 = bf2f(uv.z), v3 = bf2f(uv.w);
    float s  = v0 + v1 + v2 + v3;
    float ss = v0*v0 + v1*v1 + v2*v2 + v3*v3;
#pragma unroll
    for (int d = 1; d < 64; d <<= 1) { s += __shfl_xor(s, d); ss += __shfl_xor(ss, d); }
    const float mean = s * (1.f/256.f);
    const float rs = rsqrtf(ss * (1.f/256.f) - mean*mean + 1e-5f);
    ushort4 o;
    o.x = f2bf((v0 - mean)*rs*gv.x + bv.x);
    o.y = f2bf((v1 - mean)*rs*gv.y + bv.y);
    o.z = f2bf((v2 - mean)*rs*gv.z + bv.z);
    o.w = f2bf((v3 - mean)*rs*gv.w + bv.w);
    *(ushort4*)(Out + row*LSTR + lane*4) = o;
  }
}

__global__ __launch_bounds__(1024, 4)
void mode_stack(const u16* __restrict__ emb, const u16* __restrict__ W2cf,
  const float* __restrict__ b2c,
  const float* __restrict__ ln1_g, const float* __restrict__ ln1_b,
  const u16* __restrict__ ffn1f, const float* __restrict__ ffn_b1,
  const u16* __restrict__ ffn2f, const float* __restrict__ ffn_b2,
  const float* __restrict__ ln2_g, const float* __restrict__ ln2_b,
  const u16* __restrict__ dec1f, const float* __restrict__ dec_b1,
  const u16* __restrict__ dec2f, const float* __restrict__ dec_b2,
  const u16* __restrict__ sc1f,  const float* __restrict__ sc_b1,
  const float* __restrict__ sc_w2, const float* __restrict__ sc_b2,
  const float* __restrict__ obs, float* __restrict__ pred, float* __restrict__ score)
{
  __shared__ u16 Xs[128 * LSTR];
  __shared__ u16 Ys[128 * LSTR];
  __shared__ float obs_ls[256];
  const int tid = threadIdx.x;
  const int lane = tid & 63, w = tid >> 6;
  const int ct = w & 7, rh = w >> 3;
  const int col = lane & 31, hi = lane >> 5;
  const int r0 = blockIdx.x * 128;
  const int m  = blockIdx.y;

  f32x16 za;
#pragma unroll
  for (int i = 0; i < 16; ++i) za[i] = 0.f;

#pragma unroll
  for (int kk = 0; kk < 4; ++kk) {
    const int gi2 = tid + kk*1024;
    const int row = gi2 >> 5, grp = gi2 & 31;
    *(s16x8*)(Xs + row*LSTR + grp*8) = *(const s16x8*)(emb + (size_t)(r0 + row)*256 + grp*8);
  }
  if (tid < 256) obs_ls[tid] = obs[(size_t)(r0 + (tid >> 1))*16 + 14 + (tid & 1)];
  __syncthreads();

  { // attn-out (fused v-proj + out-proj)
    f32x16 acc[2]; acc[0] = za; acc[1] = za;
    gemm128(Xs, W2cf + (size_t)m*65536, acc, ct, rh, lane);
    epi_store128<0>(acc, b2c + m*256, Ys, ct, rh, lane);
  }
  __syncthreads();
  lnpass128(Ys, Xs, ln1_g, ln1_b, tid);   // Xs = h1
  __syncthreads();

  f32x16 h2[2]; h2[0] = za; h2[1] = za;
  for (int c4 = 0; c4 < 4; ++c4) {
    f32x16 tacc[2]; tacc[0] = za; tacc[1] = za;
    gemm128(Xs, ffn1f + (size_t)c4*65536, tacc, ct, rh, lane);
    epi_store128<1>(tacc, ffn_b1 + c4*256, Ys, ct, rh, lane);
    __syncthreads();
    gemm_ffn2_128(Ys, ffn2f, h2, c4, ct, rh, lane);
    __syncthreads();
  }
  epi_store128<0>(h2, ffn_b2, Ys, ct, rh, lane);
  __syncthreads();
  lnpass128(Ys, Xs, ln2_g, ln2_b, tid);   // Xs = mm_emb
  __syncthreads();

  f32x16 dv[2]; dv[0] = za; dv[1] = za;
  for (int c2 = 0; c2 < 2; ++c2) {
    f32x16 tacc[2]; tacc[0] = za; tacc[1] = za;
    gemm128(Xs, dec1f + (size_t)c2*65536, tacc, ct, rh, lane);
    epi_store128<2>(tacc, dec_b1 + c2*256, Ys, ct, rh, lane);
    __syncthreads();
    if (ct == 0) {   // dec2: waves 0 & 8, 2 row-tiles each, 32 cols (24 real)
#pragma unroll 4
      for (int ks = 0; ks < 16; ++ks) {
        s16x8 b = *(const s16x8*)(dec2f + ((size_t)(c2*16 + ks)*64 + lane)*8);
#pragma unroll
        for (int i = 0; i < 2; ++i) {
          s16x8 a = *(const s16x8*)(Ys + ((rh*2 + i)*32 + col)*LSTR + ks*16 + hi*8);
          dv[i] = __builtin_amdgcn_mfma_f32_32x32x16_bf16(a, b, dv[i], 0, 0, 0);
        }
      }
    }
    __syncthreads();
  }
  // predictions epilogue (deltas + last_pos) — frees dv before score head
  if (ct == 0 && col < 24) {
    const float db = dec_b2[col];
#pragma unroll
    for (int i = 0; i < 2; ++i)
#pragma unroll
      for (int r = 0; r < 16; ++r) {
        const int row = (rh*2 + i)*32 + (r&3) + 8*(r>>2) + 4*hi;
        const float lp = obs_ls[row*2 + (col & 1)];
        pred[((size_t)(r0 + row)*20 + m)*24 + col] = dv[i][r] + db + lp;
      }
  }

  if (ct < 4) { // score head layer 1: 128 cols = col-tiles 0..3 (both row-halves)
    f32x16 sacc[2]; sacc[0] = za; sacc[1] = za;
    gemm128(Xs, sc1f, sacc, ct, rh, lane);
    epi_store128<2>(sacc, sc_b1, Ys, ct, rh, lane);
  }
  __syncthreads();
  { // score head layer 2: dot(128) per row; 16 waves x 8 rows
    const float scb2 = sc_b2[0];
    const float2 w2v = *(const float2*)&sc_w2[lane*2];
#pragma unroll
    for (int i = 0; i < 8; ++i) {
      const int row = w*8 + i;
      u32 pv = *(const u32*)(Ys + row*LSTR + lane*2);
      float part = bf2f((u16)(pv & 0xFFFF))*w2v.x + bf2f((u16)(pv >> 16))*w2v.y;
#pragma unroll
      for (int d = 1; d < 64; d <<= 1) part += __shfl_xor(part, d);
      if (lane == 0) score[(size_t)(r0 + row)*20 + m] = part + scb2;
    }
  }
}

// ---------------------------------------------------------------------------
extern "C" void kernel_launch(void* const* d_in, const int* in_sizes, int n_in,
                              void* d_out, int out_size, void* d_ws, size_t ws_size,
                              hipStream_t stream)
{
  (void)in_sizes; (void)n_in; (void)out_size; (void)ws_size;
  const float* obs    = (const float*)d_in[0];
  const float* w_ih0  = (const float*)d_in[1];
  const float* w_hh0  = (const float*)d_in[2];
  const float* b_ih0  = (const float*)d_in[3];
  const float* b_hh0  = (const float*)d_in[4];
  const float* w_ih1  = (const float*)d_in[5];
  const float* w_hh1  = (const float*)d_in[6];
  const float* b_ih1  = (const float*)d_in[7];
  const float* b_hh1  = (const float*)d_in[8];
  const float* ipw    = (const float*)d_in[9];
  const float* ipb    = (const float*)d_in[10];
  const float* out_w  = (const float*)d_in[11];
  const float* out_b  = (const float*)d_in[12];
  const float* ln1_g  = (const float*)d_in[13];
  const float* ln1_b  = (const float*)d_in[14];
  const float* ffn_w1 = (const float*)d_in[15];
  const float* ffn_b1 = (const float*)d_in[16];
  const float* ffn_w2 = (const float*)d_in[17];
  const float* ffn_b2 = (const float*)d_in[18];
  const float* ln2_g  = (const float*)d_in[19];
  const float* ln2_b  = (const float*)d_in[20];
  const float* dec_w1 = (const float*)d_in[21];
  const float* dec_b1 = (const float*)d_in[22];
  const float* dec_w2 = (const float*)d_in[23];
  const float* dec_b2 = (const float*)d_in[24];
  const float* sc_w1  = (const float*)d_in[25];
  const float* sc_b1  = (const float*)d_in[26];
  const float* sc_w2  = (const float*)d_in[27];
  const float* sc_b2  = (const float*)d_in[28];

  float* outp   = (float*)d_out;
  float* pred   = outp;
  float* scoreo = outp + (size_t)8192*20*24;

  // workspace layout
  float* wsf   = (float*)d_ws;
  float* W2c   = wsf;                         // 1310720 f32
  float* b2cp  = wsf + 1310720;               // 5120 f32
  u16*   wsh   = (u16*)(wsf + 1315840);       // 16B-aligned
  u16* whh0f = wsh + 0;
  u16* wih1f = wsh + 262144;
  u16* whh1f = wsh + 524288;
  u16* W2cf  = wsh + 786432;
  u16* ffn1f = wsh + 2097152;
  u16* ffn2f = wsh + 2359296;
  u16* dec1f = wsh + 2621440;
  u16* dec2f = wsh + 2752512;
  u16* sc1f  = wsh + 2768896;
  u16* emb   = wsh + 2801664;                 // 8192*256 bf16

  w2c_kernel<<<dim3(16, 20), 256, 0, stream>>>(out_w, ipw, W2c);
  b2c_kernel<<<20, 256, 0, stream>>>(out_w, out_b, ipb, b2cp);
  wcvt_all<<<1368, 256, 0, stream>>>(w_hh0, w_ih1, w_hh1, W2c, ffn_w1, ffn_w2,
                                     dec_w1, dec_w2, sc_w1, wsh);
  lstm_fused<<<256, 512, 0, stream>>>(whh0f, wih1f, whh1f, w_ih0, b_ih0, b_hh0,
                                      b_ih1, b_hh1, obs, emb);
  mode_stack<<<dim3(64, 20), 1024, 0, stream>>>(emb, W2cf, b2cp,
      ln1_g, ln1_b, ffn1f, ffn_b1, ffn2f, ffn_b2, ln2_g, ln2_b,
      dec1f, dec_b1, dec2f, dec_b2, sc1f, sc_b1, sc_w2, sc_b2,
      obs, pred, scoreo);
}